// Round 1
// baseline (1703.504 us; speedup 1.0000x reference)
//
#include <hip/hip_runtime.h>
#include <hip/hip_bf16.h>

#define N_NODES 100000
#define N_EDGES 1600000
#define HID 128
#define INDIM 256

// ---------------------------------------------------------------------------
// degree / dinv
// ---------------------------------------------------------------------------
__global__ void k_deg_init(float* __restrict__ deg) {
    int i = blockIdx.x * blockDim.x + threadIdx.x;
    if (i < N_NODES) deg[i] = 1.0f;  // self-loop
}

__global__ void k_deg_scatter(const int* __restrict__ dst, float* __restrict__ deg) {
    for (int e = blockIdx.x * blockDim.x + threadIdx.x; e < N_EDGES;
         e += gridDim.x * blockDim.x)
        atomicAdd(&deg[dst[e]], 1.0f);
}

__global__ void k_dinv(float* __restrict__ deg) {
    int i = blockIdx.x * blockDim.x + threadIdx.x;
    if (i < N_NODES) deg[i] = rsqrtf(deg[i]);
}

// ---------------------------------------------------------------------------
// generic fp32 tiled GEMM: A[M,K] @ B[K,128]
// MODE 0: out0 = relu(A@B + bias)              (input layer)
// MODE 1: v = (A@B) * dinv[row]; out0 = v (hs); out1 = v (acc init = self-loop)
// M = 100000 divisible by BM=32, K in {256,128} divisible by BK=64 -> no guards
// ---------------------------------------------------------------------------
template <int K, int MODE>
__global__ void __launch_bounds__(256)
k_gemm(const float* __restrict__ A, const float* __restrict__ B,
       const float* __restrict__ bias, const float* __restrict__ dinv,
       float* __restrict__ out0, float* __restrict__ out1) {
    constexpr int BM = 32, BN = 128, BK = 64;
    __shared__ float As[BM][BK];        // 8 KB
    __shared__ float Bs[BK][BN + 4];    // ~33 KB (padded)
    const int t = threadIdx.x;
    const int row0 = blockIdx.x * BM;
    const int tx = t & 31;   // col group: cols tx*4 .. tx*4+3
    const int ty = t >> 5;   // row group: rows ty*4 .. ty*4+3

    float acc[4][4] = {};

    for (int k0 = 0; k0 < K; k0 += BK) {
#pragma unroll
        for (int i = 0; i < 8; ++i) {   // A tile: 32x64 = 2048 floats
            int idx = t + i * 256;
            int r = idx >> 6, c = idx & 63;
            As[r][c] = A[(size_t)(row0 + r) * K + (k0 + c)];
        }
#pragma unroll
        for (int i = 0; i < 32; ++i) {  // B tile: 64x128 = 8192 floats
            int idx = t + i * 256;
            int r = idx >> 7, c = idx & 127;
            Bs[r][c] = B[(size_t)(k0 + r) * BN + c];
        }
        __syncthreads();
#pragma unroll
        for (int kk = 0; kk < BK; ++kk) {
            float a[4], b[4];
#pragma unroll
            for (int i = 0; i < 4; ++i) a[i] = As[ty * 4 + i][kk];
#pragma unroll
            for (int j = 0; j < 4; ++j) b[j] = Bs[kk][tx * 4 + j];
#pragma unroll
            for (int i = 0; i < 4; ++i)
#pragma unroll
                for (int j = 0; j < 4; ++j) acc[i][j] += a[i] * b[j];
        }
        __syncthreads();
    }

#pragma unroll
    for (int i = 0; i < 4; ++i) {
        int r = row0 + ty * 4 + i;
        float di = (MODE == 1) ? dinv[r] : 0.0f;
#pragma unroll
        for (int j = 0; j < 4; ++j) {
            int c = tx * 4 + j;
            float v = acc[i][j];
            if (MODE == 0) {
                v = fmaxf(v + bias[c], 0.0f);
                out0[(size_t)r * 128 + c] = v;
            } else {
                v *= di;
                out0[(size_t)r * 128 + c] = v;   // hs
                out1[(size_t)r * 128 + c] = v;   // acc init (self-loop term)
            }
        }
    }
}

// ---------------------------------------------------------------------------
// edge scatter: acc[dst][c] += hs[src][c]   (128 threads per edge)
// ---------------------------------------------------------------------------
__global__ void __launch_bounds__(256)
k_scatter(const float* __restrict__ hs, float* __restrict__ acc,
          const int* __restrict__ src, const int* __restrict__ dst) {
    const int lane = threadIdx.x & 127;
    const int sub = threadIdx.x >> 7;  // 0..1
    for (int e = blockIdx.x * 2 + sub; e < N_EDGES; e += gridDim.x * 2) {
        int s = src[e];
        int d = dst[e];
        float v = hs[(size_t)s * 128 + lane];
        atomicAdd(&acc[(size_t)d * 128 + lane], v);
    }
}

// ---------------------------------------------------------------------------
// finalize: cl = relu(cl * dinv[row] + bias[col]),  vectorized float4
// ---------------------------------------------------------------------------
__global__ void k_finalize(float* __restrict__ cl, const float* __restrict__ dinv,
                           const float* __restrict__ bias) {
    int idx = blockIdx.x * blockDim.x + threadIdx.x;  // float4 index
    if (idx >= N_NODES * 32) return;
    int row = idx >> 5;
    int c4 = (idx & 31) * 4;
    float4 v = reinterpret_cast<float4*>(cl)[idx];
    float di = dinv[row];
    v.x = fmaxf(fmaf(v.x, di, bias[c4 + 0]), 0.0f);
    v.y = fmaxf(fmaf(v.y, di, bias[c4 + 1]), 0.0f);
    v.z = fmaxf(fmaf(v.z, di, bias[c4 + 2]), 0.0f);
    v.w = fmaxf(fmaf(v.w, di, bias[c4 + 3]), 0.0f);
    reinterpret_cast<float4*>(cl)[idx] = v;
}

// ---------------------------------------------------------------------------
// output head: out[n] = [h|c0|c1][n] . W_out + b_out   (one wave per node)
// ---------------------------------------------------------------------------
__global__ void __launch_bounds__(256)
k_out(const float* __restrict__ h, const float* __restrict__ c0,
      const float* __restrict__ c1, const float* __restrict__ Wout,
      const float* __restrict__ bout, float* __restrict__ out) {
    const int lane = threadIdx.x & 63;
    const int wid = threadIdx.x >> 6;  // 0..3
    for (int n = blockIdx.x * 4 + wid; n < N_NODES; n += gridDim.x * 4) {
        size_t base = (size_t)n * 128;
        float v = h[base + lane] * Wout[lane] + h[base + 64 + lane] * Wout[64 + lane] +
                  c0[base + lane] * Wout[128 + lane] + c0[base + 64 + lane] * Wout[192 + lane] +
                  c1[base + lane] * Wout[256 + lane] + c1[base + 64 + lane] * Wout[320 + lane];
#pragma unroll
        for (int off = 32; off; off >>= 1) v += __shfl_down(v, off);
        if (lane == 0) out[n] = v + bout[0];
    }
}

// ---------------------------------------------------------------------------
extern "C" void kernel_launch(void* const* d_in, const int* in_sizes, int n_in,
                              void* d_out, int out_size, void* d_ws, size_t ws_size,
                              hipStream_t stream) {
    const float* x      = (const float*)d_in[0];
    const int*   eidx   = (const int*)d_in[1];    // [2, E]; src = row 0, dst = row 1
    const float* W_in   = (const float*)d_in[2];
    const float* b_in   = (const float*)d_in[3];
    const float* W_c0   = (const float*)d_in[4];
    const float* b_c0   = (const float*)d_in[5];
    const float* W_c1   = (const float*)d_in[6];
    const float* b_c1   = (const float*)d_in[7];
    const float* W_out  = (const float*)d_in[8];
    const float* b_out  = (const float*)d_in[9];
    float* out = (float*)d_out;

    const int* src = eidx;
    const int* dst = eidx + N_EDGES;

    // workspace layout (floats)
    float* ws   = (float*)d_ws;
    float* dinv = ws;                    // N (deg then dinv, in place)
    float* h    = ws + 100352;           // N*128
    float* c0   = h  + 12800000;
    float* c1   = c0 + 12800000;
    float* hs   = c1 + 12800000;

    // degrees
    k_deg_init<<<(N_NODES + 255) / 256, 256, 0, stream>>>(dinv);
    k_deg_scatter<<<2048, 256, 0, stream>>>(dst, dinv);
    k_dinv<<<(N_NODES + 255) / 256, 256, 0, stream>>>(dinv);

    // input layer: h = relu(x @ W_in + b_in)
    k_gemm<INDIM, 0><<<N_NODES / 32, 256, 0, stream>>>(x, W_in, b_in, nullptr, h, nullptr);

    // conv0
    k_gemm<HID, 1><<<N_NODES / 32, 256, 0, stream>>>(h, W_c0, nullptr, dinv, hs, c0);
    k_scatter<<<8192, 256, 0, stream>>>(hs, c0, src, dst);
    k_finalize<<<(N_NODES * 32 + 255) / 256, 256, 0, stream>>>(c0, dinv, b_c0);

    // conv1
    k_gemm<HID, 1><<<N_NODES / 32, 256, 0, stream>>>(c0, W_c1, nullptr, dinv, hs, c1);
    k_scatter<<<8192, 256, 0, stream>>>(hs, c1, src, dst);
    k_finalize<<<(N_NODES * 32 + 255) / 256, 256, 0, stream>>>(c1, dinv, b_c1);

    // output head
    k_out<<<1024, 256, 0, stream>>>(h, c0, c1, W_out, b_out, out);
}

// Round 2
// 951.488 us; speedup vs baseline: 1.7904x; 1.7904x over previous
//
#include <hip/hip_runtime.h>
#include <hip/hip_bf16.h>

#define N_NODES 100000
#define N_EDGES 1600000
#define HID 128
#define INDIM 256

// ---------------------------------------------------------------------------
// CSR build: in-degree count -> exclusive scan -> cursor fill
// ---------------------------------------------------------------------------
__global__ void k_count_init(int* __restrict__ cnt) {
    int i = blockIdx.x * blockDim.x + threadIdx.x;
    if (i < N_NODES) cnt[i] = 0;
}

__global__ void k_count(const int* __restrict__ dst, int* __restrict__ cnt) {
    for (int e = blockIdx.x * blockDim.x + threadIdx.x; e < N_EDGES;
         e += gridDim.x * blockDim.x)
        atomicAdd(&cnt[dst[e]], 1);
}

// single-block exclusive scan over 100k counts; also emits cursor copy and
// dinv[i] = rsqrt(deg_in + 1)  (self-loop included in normalization)
__global__ void __launch_bounds__(1024)
k_scan(const int* __restrict__ cnt, int* __restrict__ off, int* __restrict__ cursor,
       float* __restrict__ dinv) {
    __shared__ int part[1024];
    const int t = threadIdx.x;
    constexpr int CH = (N_NODES + 1023) / 1024;  // 98
    int b0 = t * CH;
    int b1 = b0 + CH; if (b1 > N_NODES) b1 = N_NODES;
    int s = 0;
    for (int i = b0; i < b1; ++i) s += cnt[i];
    part[t] = s;
    __syncthreads();
    for (int o = 1; o < 1024; o <<= 1) {
        int u = (t >= o) ? part[t - o] : 0;
        __syncthreads();
        part[t] += u;
        __syncthreads();
    }
    int run = part[t] - s;  // exclusive prefix of this chunk
    for (int i = b0; i < b1; ++i) {
        int c = cnt[i];
        off[i] = run;
        cursor[i] = run;
        dinv[i] = rsqrtf((float)(c + 1));
        run += c;
    }
    if (t == 1023) off[N_NODES] = part[1023];
}

__global__ void k_fill(const int* __restrict__ src, const int* __restrict__ dst,
                       int* __restrict__ cursor, int* __restrict__ csr) {
    for (int e = blockIdx.x * blockDim.x + threadIdx.x; e < N_EDGES;
         e += gridDim.x * blockDim.x) {
        int p = atomicAdd(&cursor[dst[e]], 1);
        csr[p] = src[e];
    }
}

// ---------------------------------------------------------------------------
// generic fp32 tiled GEMM: A[M,K] @ B[K,128]
// MODE 0: out0 = relu(A@B + bias)          (input layer)
// MODE 1: out0 = (A@B) * dinv[row]         (hs for gather)
// ---------------------------------------------------------------------------
template <int K, int MODE>
__global__ void __launch_bounds__(256)
k_gemm(const float* __restrict__ A, const float* __restrict__ B,
       const float* __restrict__ bias, const float* __restrict__ dinv,
       float* __restrict__ out0) {
    constexpr int BM = 32, BN = 128, BK = 64;
    __shared__ float As[BM][BK];
    __shared__ float Bs[BK][BN + 4];
    const int t = threadIdx.x;
    const int row0 = blockIdx.x * BM;
    const int tx = t & 31;
    const int ty = t >> 5;

    float acc[4][4] = {};

    for (int k0 = 0; k0 < K; k0 += BK) {
#pragma unroll
        for (int i = 0; i < 8; ++i) {
            int idx = t + i * 256;
            int r = idx >> 6, c = idx & 63;
            As[r][c] = A[(size_t)(row0 + r) * K + (k0 + c)];
        }
#pragma unroll
        for (int i = 0; i < 32; ++i) {
            int idx = t + i * 256;
            int r = idx >> 7, c = idx & 127;
            Bs[r][c] = B[(size_t)(k0 + r) * BN + c];
        }
        __syncthreads();
#pragma unroll
        for (int kk = 0; kk < BK; ++kk) {
            float a[4], b[4];
#pragma unroll
            for (int i = 0; i < 4; ++i) a[i] = As[ty * 4 + i][kk];
#pragma unroll
            for (int j = 0; j < 4; ++j) b[j] = Bs[kk][tx * 4 + j];
#pragma unroll
            for (int i = 0; i < 4; ++i)
#pragma unroll
                for (int j = 0; j < 4; ++j) acc[i][j] += a[i] * b[j];
        }
        __syncthreads();
    }

#pragma unroll
    for (int i = 0; i < 4; ++i) {
        int r = row0 + ty * 4 + i;
        float di = (MODE == 1) ? dinv[r] : 0.0f;
#pragma unroll
        for (int j = 0; j < 4; ++j) {
            int c = tx * 4 + j;
            float v = acc[i][j];
            if (MODE == 0) {
                v = fmaxf(v + bias[c], 0.0f);
            } else {
                v *= di;
            }
            out0[(size_t)r * 128 + c] = v;
        }
    }
}

// ---------------------------------------------------------------------------
// gather-aggregate: one wave per node, float2 per lane (128 channels)
// out[n] = relu((hs[n] + sum_{s in N_in(n)} hs[s]) * dinv[n] + bias)
// ---------------------------------------------------------------------------
__global__ void __launch_bounds__(256)
k_gather(const float* __restrict__ hs, const int* __restrict__ csr,
         const int* __restrict__ off, const float* __restrict__ dinv,
         const float* __restrict__ bias, float* __restrict__ out) {
    const int wid = threadIdx.x >> 6;
    const int lane = threadIdx.x & 63;
    const int n = blockIdx.x * 4 + wid;
    if (n >= N_NODES) return;

    const float2* hs2 = (const float2*)hs;
    float2 acc = hs2[(size_t)n * 64 + lane];  // self-loop term
    const int beg = off[n], end = off[n + 1];

    for (int b = beg; b < end; b += 64) {
        int m = end - b; if (m > 64) m = 64;
        int idx = (lane < m) ? csr[b + lane] : 0;
        for (int i = 0; i < m; ++i) {
            int s = __shfl(idx, i);
            float2 v = hs2[(size_t)s * 64 + lane];
            acc.x += v.x;
            acc.y += v.y;
        }
    }

    float di = dinv[n];
    float2 bb = ((const float2*)bias)[lane];
    float2 r;
    r.x = fmaxf(fmaf(acc.x, di, bb.x), 0.0f);
    r.y = fmaxf(fmaf(acc.y, di, bb.y), 0.0f);
    ((float2*)out)[(size_t)n * 64 + lane] = r;
}

// ---------------------------------------------------------------------------
// output head: out[n] = [h|c0|c1][n] . W_out + b_out   (one wave per node)
// ---------------------------------------------------------------------------
__global__ void __launch_bounds__(256)
k_out(const float* __restrict__ h, const float* __restrict__ c0,
      const float* __restrict__ c1, const float* __restrict__ Wout,
      const float* __restrict__ bout, float* __restrict__ out) {
    const int lane = threadIdx.x & 63;
    const int wid = threadIdx.x >> 6;
    for (int n = blockIdx.x * 4 + wid; n < N_NODES; n += gridDim.x * 4) {
        size_t base = (size_t)n * 128;
        float v = h[base + lane] * Wout[lane] + h[base + 64 + lane] * Wout[64 + lane] +
                  c0[base + lane] * Wout[128 + lane] + c0[base + 64 + lane] * Wout[192 + lane] +
                  c1[base + lane] * Wout[256 + lane] + c1[base + 64 + lane] * Wout[320 + lane];
#pragma unroll
        for (int off = 32; off; off >>= 1) v += __shfl_down(v, off);
        if (lane == 0) out[n] = v + bout[0];
    }
}

// ---------------------------------------------------------------------------
extern "C" void kernel_launch(void* const* d_in, const int* in_sizes, int n_in,
                              void* d_out, int out_size, void* d_ws, size_t ws_size,
                              hipStream_t stream) {
    const float* x     = (const float*)d_in[0];
    const int*   eidx  = (const int*)d_in[1];
    const float* W_in  = (const float*)d_in[2];
    const float* b_in  = (const float*)d_in[3];
    const float* W_c0  = (const float*)d_in[4];
    const float* b_c0  = (const float*)d_in[5];
    const float* W_c1  = (const float*)d_in[6];
    const float* b_c1  = (const float*)d_in[7];
    const float* W_out = (const float*)d_in[8];
    const float* b_out = (const float*)d_in[9];
    float* out = (float*)d_out;

    const int* src = eidx;
    const int* dst = eidx + N_EDGES;

    // workspace layout
    float* ws   = (float*)d_ws;
    float* dinv = ws;                        // N
    float* h    = ws + 100352;               // N*128
    float* c0   = h  + 12800000;
    float* c1   = c0 + 12800000;
    float* hs   = c1 + 12800000;
    int*   cnt    = (int*)(hs + 12800000);   // N
    int*   off    = cnt + 100352;            // N+1
    int*   cursor = off + 100352;            // N
    int*   csr    = cursor + 100352;         // E

    // CSR build
    k_count_init<<<(N_NODES + 255) / 256, 256, 0, stream>>>(cnt);
    k_count<<<2048, 256, 0, stream>>>(dst, cnt);
    k_scan<<<1, 1024, 0, stream>>>(cnt, off, cursor, dinv);
    k_fill<<<2048, 256, 0, stream>>>(src, dst, cursor, csr);

    // input layer: h = relu(x @ W_in + b_in)
    k_gemm<INDIM, 0><<<N_NODES / 32, 256, 0, stream>>>(x, W_in, b_in, nullptr, h);

    // conv0
    k_gemm<HID, 1><<<N_NODES / 32, 256, 0, stream>>>(h, W_c0, nullptr, dinv, hs);
    k_gather<<<(N_NODES + 3) / 4, 256, 0, stream>>>(hs, csr, off, dinv, b_c0, c0);

    // conv1
    k_gemm<HID, 1><<<N_NODES / 32, 256, 0, stream>>>(c0, W_c1, nullptr, dinv, hs);
    k_gather<<<(N_NODES + 3) / 4, 256, 0, stream>>>(hs, csr, off, dinv, b_c1, c1);

    // output head
    k_out<<<1024, 256, 0, stream>>>(h, c0, c1, W_out, b_out, out);
}

// Round 3
// 692.175 us; speedup vs baseline: 2.4611x; 1.3746x over previous
//
#include <hip/hip_runtime.h>
#include <hip/hip_bf16.h>

#define N_NODES 100000
#define N_EDGES 1600000
#define HID 128
#define INDIM 256
#define SCAN_NB 98   // ceil(100000 / 1024)

// ---------------------------------------------------------------------------
// CSR build: in-degree count -> 3-phase exclusive scan -> cursor fill
// ---------------------------------------------------------------------------
__global__ void k_count_init(int* __restrict__ cnt) {
    int i = blockIdx.x * blockDim.x + threadIdx.x;
    if (i < N_NODES) cnt[i] = 0;
}

__global__ void k_count(const int* __restrict__ dst, int* __restrict__ cnt) {
    for (int e = blockIdx.x * blockDim.x + threadIdx.x; e < N_EDGES;
         e += gridDim.x * blockDim.x)
        atomicAdd(&cnt[dst[e]], 1);
}

// phase A: per-block (1024-node chunk) total
__global__ void __launch_bounds__(256)
k_scanA(const int* __restrict__ cnt, int* __restrict__ bsum) {
    __shared__ int sh[256];
    const int b = blockIdx.x, t = threadIdx.x;
    int base = b * 1024 + t * 4;
    int s = 0;
#pragma unroll
    for (int j = 0; j < 4; ++j) {
        int i = base + j;
        if (i < N_NODES) s += cnt[i];
    }
    sh[t] = s;
    __syncthreads();
    for (int o = 128; o; o >>= 1) {
        if (t < o) sh[t] += sh[t + o];
        __syncthreads();
    }
    if (t == 0) bsum[b] = sh[0];
}

// phase B: exclusive scan of the 98 block sums (single tiny block)
__global__ void __launch_bounds__(128)
k_scanB(int* __restrict__ bsum, int* __restrict__ off) {
    __shared__ int sh[128];
    const int t = threadIdx.x;
    int v = (t < SCAN_NB) ? bsum[t] : 0;
    sh[t] = v;
    __syncthreads();
    for (int o = 1; o < 128; o <<= 1) {
        int u = (t >= o) ? sh[t - o] : 0;
        __syncthreads();
        sh[t] += u;
        __syncthreads();
    }
    if (t < SCAN_NB) bsum[t] = sh[t] - v;  // exclusive
    if (t == 0) off[N_NODES] = N_EDGES;    // known total (all dst in range)
}

// phase C: in-block exclusive scan + block offset; emit off/cursor/dinv
__global__ void __launch_bounds__(256)
k_scanC(const int* __restrict__ cnt, const int* __restrict__ bsum,
        int* __restrict__ off, int* __restrict__ cursor, float* __restrict__ dinv) {
    __shared__ int sh[256];
    const int b = blockIdx.x, t = threadIdx.x;
    int base = b * 1024 + t * 4;
    int loc[4];
    int s = 0;
#pragma unroll
    for (int j = 0; j < 4; ++j) {
        int i = base + j;
        loc[j] = (i < N_NODES) ? cnt[i] : 0;
        s += loc[j];
    }
    sh[t] = s;
    __syncthreads();
    for (int o = 1; o < 256; o <<= 1) {
        int u = (t >= o) ? sh[t - o] : 0;
        __syncthreads();
        sh[t] += u;
        __syncthreads();
    }
    int run = bsum[b] + sh[t] - s;
#pragma unroll
    for (int j = 0; j < 4; ++j) {
        int i = base + j;
        if (i < N_NODES) {
            off[i] = run;
            cursor[i] = run;
            dinv[i] = rsqrtf((float)(loc[j] + 1));
            run += loc[j];
        }
    }
}

__global__ void k_fill(const int* __restrict__ src, const int* __restrict__ dst,
                       int* __restrict__ cursor, int* __restrict__ csr) {
    for (int e = blockIdx.x * blockDim.x + threadIdx.x; e < N_EDGES;
         e += gridDim.x * blockDim.x) {
        int p = atomicAdd(&cursor[dst[e]], 1);
        csr[p] = src[e];
    }
}

// ---------------------------------------------------------------------------
// generic fp32 tiled GEMM: A[M,K] @ B[K,128]
// MODE 0: out0 = relu(A@B + bias)          (input layer)
// MODE 1: out0 = (A@B) * dinv[row]         (hs for gather)
// ---------------------------------------------------------------------------
template <int K, int MODE>
__global__ void __launch_bounds__(256)
k_gemm(const float* __restrict__ A, const float* __restrict__ B,
       const float* __restrict__ bias, const float* __restrict__ dinv,
       float* __restrict__ out0) {
    constexpr int BM = 32, BN = 128, BK = 64;
    __shared__ float As[BM][BK];
    __shared__ float Bs[BK][BN + 4];
    const int t = threadIdx.x;
    const int row0 = blockIdx.x * BM;
    const int tx = t & 31;
    const int ty = t >> 5;

    float acc[4][4] = {};

    for (int k0 = 0; k0 < K; k0 += BK) {
#pragma unroll
        for (int i = 0; i < 8; ++i) {
            int idx = t + i * 256;
            int r = idx >> 6, c = idx & 63;
            As[r][c] = A[(size_t)(row0 + r) * K + (k0 + c)];
        }
#pragma unroll
        for (int i = 0; i < 32; ++i) {
            int idx = t + i * 256;
            int r = idx >> 7, c = idx & 127;
            Bs[r][c] = B[(size_t)(k0 + r) * BN + c];
        }
        __syncthreads();
#pragma unroll
        for (int kk = 0; kk < BK; ++kk) {
            float a[4], b[4];
#pragma unroll
            for (int i = 0; i < 4; ++i) a[i] = As[ty * 4 + i][kk];
#pragma unroll
            for (int j = 0; j < 4; ++j) b[j] = Bs[kk][tx * 4 + j];
#pragma unroll
            for (int i = 0; i < 4; ++i)
#pragma unroll
                for (int j = 0; j < 4; ++j) acc[i][j] += a[i] * b[j];
        }
        __syncthreads();
    }

#pragma unroll
    for (int i = 0; i < 4; ++i) {
        int r = row0 + ty * 4 + i;
        float di = (MODE == 1) ? dinv[r] : 0.0f;
#pragma unroll
        for (int j = 0; j < 4; ++j) {
            int c = tx * 4 + j;
            float v = acc[i][j];
            if (MODE == 0) {
                v = fmaxf(v + bias[c], 0.0f);
            } else {
                v *= di;
            }
            out0[(size_t)r * 128 + c] = v;
        }
    }
}

// ---------------------------------------------------------------------------
// gather-aggregate: one wave per node, float2 per lane (128 channels)
// out[n] = relu((hs[n] + sum_{s in N_in(n)} hs[s]) * dinv[n] + bias)
// ---------------------------------------------------------------------------
__global__ void __launch_bounds__(256)
k_gather(const float* __restrict__ hs, const int* __restrict__ csr,
         const int* __restrict__ off, const float* __restrict__ dinv,
         const float* __restrict__ bias, float* __restrict__ out) {
    const int wid = threadIdx.x >> 6;
    const int lane = threadIdx.x & 63;
    const int n = blockIdx.x * 4 + wid;
    if (n >= N_NODES) return;

    const float2* hs2 = (const float2*)hs;
    float2 acc = hs2[(size_t)n * 64 + lane];  // self-loop term
    const int beg = off[n], end = off[n + 1];

    for (int b = beg; b < end; b += 64) {
        int m = end - b; if (m > 64) m = 64;
        int idx = (lane < m) ? csr[b + lane] : 0;
        for (int i = 0; i < m; ++i) {
            int s = __shfl(idx, i);
            float2 v = hs2[(size_t)s * 64 + lane];
            acc.x += v.x;
            acc.y += v.y;
        }
    }

    float di = dinv[n];
    float2 bb = ((const float2*)bias)[lane];
    float2 r;
    r.x = fmaxf(fmaf(acc.x, di, bb.x), 0.0f);
    r.y = fmaxf(fmaf(acc.y, di, bb.y), 0.0f);
    ((float2*)out)[(size_t)n * 64 + lane] = r;
}

// ---------------------------------------------------------------------------
// output head: out[n] = [h|c0|c1][n] . W_out + b_out   (one wave per node)
// ---------------------------------------------------------------------------
__global__ void __launch_bounds__(256)
k_out(const float* __restrict__ h, const float* __restrict__ c0,
      const float* __restrict__ c1, const float* __restrict__ Wout,
      const float* __restrict__ bout, float* __restrict__ out) {
    const int lane = threadIdx.x & 63;
    const int wid = threadIdx.x >> 6;
    for (int n = blockIdx.x * 4 + wid; n < N_NODES; n += gridDim.x * 4) {
        size_t base = (size_t)n * 128;
        float v = h[base + lane] * Wout[lane] + h[base + 64 + lane] * Wout[64 + lane] +
                  c0[base + lane] * Wout[128 + lane] + c0[base + 64 + lane] * Wout[192 + lane] +
                  c1[base + lane] * Wout[256 + lane] + c1[base + 64 + lane] * Wout[320 + lane];
#pragma unroll
        for (int off = 32; off; off >>= 1) v += __shfl_down(v, off);
        if (lane == 0) out[n] = v + bout[0];
    }
}

// ---------------------------------------------------------------------------
extern "C" void kernel_launch(void* const* d_in, const int* in_sizes, int n_in,
                              void* d_out, int out_size, void* d_ws, size_t ws_size,
                              hipStream_t stream) {
    const float* x     = (const float*)d_in[0];
    const int*   eidx  = (const int*)d_in[1];
    const float* W_in  = (const float*)d_in[2];
    const float* b_in  = (const float*)d_in[3];
    const float* W_c0  = (const float*)d_in[4];
    const float* b_c0  = (const float*)d_in[5];
    const float* W_c1  = (const float*)d_in[6];
    const float* b_c1  = (const float*)d_in[7];
    const float* W_out = (const float*)d_in[8];
    const float* b_out = (const float*)d_in[9];
    float* out = (float*)d_out;

    const int* src = eidx;
    const int* dst = eidx + N_EDGES;

    // workspace layout
    float* ws   = (float*)d_ws;
    float* dinv = ws;                        // N
    float* h    = ws + 100352;               // N*128
    float* c0   = h  + 12800000;
    float* c1   = c0 + 12800000;
    float* hs   = c1 + 12800000;
    int*   cnt    = (int*)(hs + 12800000);   // N
    int*   off    = cnt + 100352;            // N+1
    int*   cursor = off + 100352;            // N
    int*   csr    = cursor + 100352;         // E
    int*   bsum   = csr + N_EDGES;           // SCAN_NB

    // CSR build
    k_count_init<<<(N_NODES + 255) / 256, 256, 0, stream>>>(cnt);
    k_count<<<2048, 256, 0, stream>>>(dst, cnt);
    k_scanA<<<SCAN_NB, 256, 0, stream>>>(cnt, bsum);
    k_scanB<<<1, 128, 0, stream>>>(bsum, off);
    k_scanC<<<SCAN_NB, 256, 0, stream>>>(cnt, bsum, off, cursor, dinv);
    k_fill<<<2048, 256, 0, stream>>>(src, dst, cursor, csr);

    // input layer: h = relu(x @ W_in + b_in)
    k_gemm<INDIM, 0><<<N_NODES / 32, 256, 0, stream>>>(x, W_in, b_in, nullptr, h);

    // conv0
    k_gemm<HID, 1><<<N_NODES / 32, 256, 0, stream>>>(h, W_c0, nullptr, dinv, hs);
    k_gather<<<(N_NODES + 3) / 4, 256, 0, stream>>>(hs, csr, off, dinv, b_c0, c0);

    // conv1
    k_gemm<HID, 1><<<N_NODES / 32, 256, 0, stream>>>(c0, W_c1, nullptr, dinv, hs);
    k_gather<<<(N_NODES + 3) / 4, 256, 0, stream>>>(hs, csr, off, dinv, b_c1, c1);

    // output head
    k_out<<<1024, 256, 0, stream>>>(h, c0, c1, W_out, b_out, out);
}

// Round 4
// 497.708 us; speedup vs baseline: 3.4227x; 1.3907x over previous
//
#include <hip/hip_runtime.h>
#include <hip/hip_bf16.h>

#define M_NODES 100000
#define N_EDGES 1600000
#define SCAN_NB 98   // ceil(100000 / 1024)

typedef __attribute__((ext_vector_type(8))) short short8;
typedef __attribute__((ext_vector_type(4))) float f32x4;
typedef __attribute__((address_space(3))) void lds_t;
typedef const __attribute__((address_space(1))) void gld_t;

__device__ __forceinline__ ushort f2bf(float f) {
    union { float f; uint u; } x; x.f = f;
    uint r = x.u + 0x7fffu + ((x.u >> 16) & 1u);   // RNE
    return (ushort)(r >> 16);
}
__device__ __forceinline__ float bflo(uint v) {
    union { uint u; float f; } x; x.u = v << 16; return x.f;
}
__device__ __forceinline__ float bfhi(uint v) {
    union { uint u; float f; } x; x.u = v & 0xffff0000u; return x.f;
}

// ---------------------------------------------------------------------------
// CSR build: in-degree count -> 3-phase exclusive scan -> cursor fill
// ---------------------------------------------------------------------------
__global__ void k_count_init(int* __restrict__ cnt) {
    int i = blockIdx.x * blockDim.x + threadIdx.x;
    if (i < M_NODES) cnt[i] = 0;
}

__global__ void k_count(const int* __restrict__ dst, int* __restrict__ cnt) {
    for (int e = blockIdx.x * blockDim.x + threadIdx.x; e < N_EDGES;
         e += gridDim.x * blockDim.x)
        atomicAdd(&cnt[dst[e]], 1);
}

__global__ void __launch_bounds__(256)
k_scanA(const int* __restrict__ cnt, int* __restrict__ bsum) {
    __shared__ int sh[256];
    const int b = blockIdx.x, t = threadIdx.x;
    int base = b * 1024 + t * 4;
    int s = 0;
#pragma unroll
    for (int j = 0; j < 4; ++j) {
        int i = base + j;
        if (i < M_NODES) s += cnt[i];
    }
    sh[t] = s;
    __syncthreads();
    for (int o = 128; o; o >>= 1) {
        if (t < o) sh[t] += sh[t + o];
        __syncthreads();
    }
    if (t == 0) bsum[b] = sh[0];
}

__global__ void __launch_bounds__(128)
k_scanB(int* __restrict__ bsum, int* __restrict__ off) {
    __shared__ int sh[128];
    const int t = threadIdx.x;
    int v = (t < SCAN_NB) ? bsum[t] : 0;
    sh[t] = v;
    __syncthreads();
    for (int o = 1; o < 128; o <<= 1) {
        int u = (t >= o) ? sh[t - o] : 0;
        __syncthreads();
        sh[t] += u;
        __syncthreads();
    }
    if (t < SCAN_NB) bsum[t] = sh[t] - v;  // exclusive
    if (t == 0) off[M_NODES] = N_EDGES;
}

__global__ void __launch_bounds__(256)
k_scanC(const int* __restrict__ cnt, const int* __restrict__ bsum,
        int* __restrict__ off, int* __restrict__ cursor, float* __restrict__ dinv) {
    __shared__ int sh[256];
    const int b = blockIdx.x, t = threadIdx.x;
    int base = b * 1024 + t * 4;
    int loc[4];
    int s = 0;
#pragma unroll
    for (int j = 0; j < 4; ++j) {
        int i = base + j;
        loc[j] = (i < M_NODES) ? cnt[i] : 0;
        s += loc[j];
    }
    sh[t] = s;
    __syncthreads();
    for (int o = 1; o < 256; o <<= 1) {
        int u = (t >= o) ? sh[t - o] : 0;
        __syncthreads();
        sh[t] += u;
        __syncthreads();
    }
    int run = bsum[b] + sh[t] - s;
#pragma unroll
    for (int j = 0; j < 4; ++j) {
        int i = base + j;
        if (i < M_NODES) {
            off[i] = run;
            cursor[i] = run;
            dinv[i] = rsqrtf((float)(loc[j] + 1));
            run += loc[j];
        }
    }
}

__global__ void k_fill(const int* __restrict__ src, const int* __restrict__ dst,
                       int* __restrict__ cursor, int* __restrict__ csr) {
    for (int e = blockIdx.x * blockDim.x + threadIdx.x; e < N_EDGES;
         e += gridDim.x * blockDim.x) {
        int p = atomicAdd(&cursor[dst[e]], 1);
        csr[p] = src[e];
    }
}

// ---------------------------------------------------------------------------
// weight prep: Wt[c][k] = bf16(W[k][c])   (transpose + convert, tiny)
// ---------------------------------------------------------------------------
__global__ void k_prep(const float* __restrict__ W, ushort* __restrict__ Wt, int K) {
    int i = blockIdx.x * blockDim.x + threadIdx.x;
    if (i < 128 * K) {
        int c = i / K, k = i - c * K;
        Wt[i] = f2bf(W[(size_t)k * 128 + c]);
    }
}

// ---------------------------------------------------------------------------
// MFMA GEMM: A[M,K] @ B[K,128], B pre-transposed bf16 Bt[128][K].
// 128x128 tile, BK=64, 4 waves (2x2), 16x16x32 bf16 MFMA, 4x4 frags/wave.
// MODE 0: out = bf16(relu(A@B + bias));  MODE 1: out = bf16((A@B)*dinv[row])
// AF32: A is fp32 (reg-staged + converted); else A is bf16 (global_load_lds).
// ---------------------------------------------------------------------------
template <int K, int MODE, bool AF32>
__global__ void __launch_bounds__(256)
k_gemm(const void* __restrict__ Av, const ushort* __restrict__ Bt,
       const float* __restrict__ bias, const float* __restrict__ dinv,
       ushort* __restrict__ out) {
    __shared__ ushort As[128 * 64];   // [row][k] 16 KB
    __shared__ ushort Bs[128 * 64];   // [col][k] 16 KB
    const int t = threadIdx.x;
    const int lane = t & 63, w = t >> 6;
    const int wr = w >> 1, wc = w & 1;
    const int l15 = lane & 15, l4 = lane >> 4;
    const int row0 = blockIdx.x * 128;

    f32x4 acc[4][4] = {};

    for (int k0 = 0; k0 < K; k0 += 64) {
        // B tile: linear LDS, 4 rounds x 256 thr x 16 B
#pragma unroll
        for (int i = 0; i < 4; ++i) {
            int idx = (i * 256 + t) * 8;          // bf16 elem index in tile
            int col = idx >> 6, kc = idx & 63;
            __builtin_amdgcn_global_load_lds(
                (gld_t*)(Bt + (size_t)col * K + k0 + kc),
                (lds_t*)(Bs + idx), 16, 0, 0);
        }
        if (AF32) {
            const float* A = (const float*)Av;
#pragma unroll
            for (int i = 0; i < 4; ++i) {
                int idx = (i * 256 + t) * 8;
                int r = idx >> 6, c = idx & 63;
                int gr = row0 + r; gr = gr < M_NODES ? gr : M_NODES - 1;
                const float4* gp = (const float4*)(A + (size_t)gr * K + k0 + c);
                float4 v0 = gp[0], v1 = gp[1];
                short8 p;
                p[0] = (short)f2bf(v0.x); p[1] = (short)f2bf(v0.y);
                p[2] = (short)f2bf(v0.z); p[3] = (short)f2bf(v0.w);
                p[4] = (short)f2bf(v1.x); p[5] = (short)f2bf(v1.y);
                p[6] = (short)f2bf(v1.z); p[7] = (short)f2bf(v1.w);
                *reinterpret_cast<short8*>(&As[idx]) = p;
            }
        } else {
            const ushort* A = (const ushort*)Av;
#pragma unroll
            for (int i = 0; i < 4; ++i) {
                int idx = (i * 256 + t) * 8;
                int r = idx >> 6, c = idx & 63;
                int gr = row0 + r; gr = gr < M_NODES ? gr : M_NODES - 1;
                __builtin_amdgcn_global_load_lds(
                    (gld_t*)(A + (size_t)gr * K + k0 + c),
                    (lds_t*)(As + idx), 16, 0, 0);
            }
        }
        __syncthreads();
#pragma unroll
        for (int kk = 0; kk < 2; ++kk) {
            short8 af[4], bw[4];
#pragma unroll
            for (int m = 0; m < 4; ++m)
                af[m] = *reinterpret_cast<const short8*>(
                    &As[(wr * 64 + m * 16 + l15) * 64 + kk * 32 + l4 * 8]);
#pragma unroll
            for (int n = 0; n < 4; ++n)
                bw[n] = *reinterpret_cast<const short8*>(
                    &Bs[(wc * 64 + n * 16 + l15) * 64 + kk * 32 + l4 * 8]);
#pragma unroll
            for (int m = 0; m < 4; ++m)
#pragma unroll
                for (int n = 0; n < 4; ++n)
                    acc[m][n] = __builtin_amdgcn_mfma_f32_16x16x32_bf16(
                        af[m], bw[n], acc[m][n], 0, 0, 0);
        }
        __syncthreads();
    }

    // epilogue: C[row][col], col = lane&15, row = (lane>>4)*4 + j
#pragma unroll
    for (int m = 0; m < 4; ++m) {
#pragma unroll
        for (int j = 0; j < 4; ++j) {
            int r = row0 + wr * 64 + m * 16 + l4 * 4 + j;
            if (r < M_NODES) {
                float sc = (MODE == 1) ? dinv[r] : 0.f;
#pragma unroll
                for (int n = 0; n < 4; ++n) {
                    int c = wc * 64 + n * 16 + l15;
                    float v = acc[m][n][j];
                    if (MODE == 0) v = fmaxf(v + bias[c], 0.f);
                    else v *= sc;
                    out[(size_t)r * 128 + c] = f2bf(v);
                }
            }
        }
    }
}

// ---------------------------------------------------------------------------
// gather-aggregate (bf16): one wave per node, uint (2 bf16) per lane
// out[n] = bf16(relu((hs[n] + sum_{s in N(n)} hs[s]) * dinv[n] + bias))
// ---------------------------------------------------------------------------
__global__ void __launch_bounds__(256)
k_gather(const ushort* __restrict__ hs, const int* __restrict__ csr,
         const int* __restrict__ off, const float* __restrict__ dinv,
         const float* __restrict__ bias, ushort* __restrict__ out) {
    const int wid = threadIdx.x >> 6;
    const int lane = threadIdx.x & 63;
    const int n = blockIdx.x * 4 + wid;
    if (n >= M_NODES) return;

    const uint* hs2 = (const uint*)hs;
    uint self = hs2[(size_t)n * 64 + lane];
    float ax = bflo(self), ay = bfhi(self);
    const int beg = off[n], end = off[n + 1];

    for (int b = beg; b < end; b += 64) {
        int m = end - b; if (m > 64) m = 64;
        int idx = (lane < m) ? csr[b + lane] : 0;
        for (int i = 0; i < m; ++i) {
            int s = __shfl(idx, i);
            uint v = hs2[(size_t)s * 64 + lane];
            ax += bflo(v);
            ay += bfhi(v);
        }
    }

    float di = dinv[n];
    float2 bb = ((const float2*)bias)[lane];
    uint rx = f2bf(fmaxf(fmaf(ax, di, bb.x), 0.f));
    uint ry = f2bf(fmaxf(fmaf(ay, di, bb.y), 0.f));
    ((uint*)out)[(size_t)n * 64 + lane] = rx | (ry << 16);
}

// ---------------------------------------------------------------------------
// output head (bf16 inputs): out[n] = [h|c0|c1][n] . W_out + b_out
// ---------------------------------------------------------------------------
__global__ void __launch_bounds__(256)
k_out(const ushort* __restrict__ h, const ushort* __restrict__ c0,
      const ushort* __restrict__ c1, const float* __restrict__ Wout,
      const float* __restrict__ bout, float* __restrict__ out) {
    const int lane = threadIdx.x & 63;
    const int wid = threadIdx.x >> 6;
    for (int n = blockIdx.x * 4 + wid; n < M_NODES; n += gridDim.x * 4) {
        size_t base = (size_t)n * 64;
        uint a = ((const uint*)h)[base + lane];
        uint b = ((const uint*)c0)[base + lane];
        uint c = ((const uint*)c1)[base + lane];
        int ch = lane * 2;
        float v = bflo(a) * Wout[ch]       + bfhi(a) * Wout[ch + 1] +
                  bflo(b) * Wout[128 + ch] + bfhi(b) * Wout[128 + ch + 1] +
                  bflo(c) * Wout[256 + ch] + bfhi(c) * Wout[256 + ch + 1];
#pragma unroll
        for (int o = 32; o; o >>= 1) v += __shfl_down(v, o);
        if (lane == 0) out[n] = v + bout[0];
    }
}

// ---------------------------------------------------------------------------
extern "C" void kernel_launch(void* const* d_in, const int* in_sizes, int n_in,
                              void* d_out, int out_size, void* d_ws, size_t ws_size,
                              hipStream_t stream) {
    const float* x     = (const float*)d_in[0];
    const int*   eidx  = (const int*)d_in[1];
    const float* W_in  = (const float*)d_in[2];
    const float* b_in  = (const float*)d_in[3];
    const float* W_c0  = (const float*)d_in[4];
    const float* b_c0  = (const float*)d_in[5];
    const float* W_c1  = (const float*)d_in[6];
    const float* b_c1  = (const float*)d_in[7];
    const float* W_out = (const float*)d_in[8];
    const float* b_out = (const float*)d_in[9];
    float* out = (float*)d_out;

    const int* src = eidx;
    const int* dst = eidx + N_EDGES;

    // workspace layout (4-byte units)
    float*  ws     = (float*)d_ws;
    float*  dinv   = ws;                            // 100352
    int*    cnt    = (int*)(ws + 100352);           // 100352
    int*    off    = (int*)(ws + 200704);           // 100352 (N+1 used)
    int*    cursor = (int*)(ws + 301056);           // 100352
    int*    csr    = (int*)(ws + 401408);           // 1600000
    int*    bsum   = (int*)(ws + 2001408);          // 128
    ushort* Wt_in  = (ushort*)(ws + 2001536);       // 128*256
    ushort* Wt_c0  = (ushort*)(ws + 2017920);       // 128*128
    ushort* Wt_c1  = (ushort*)(ws + 2026112);       // 128*128
    ushort* h      = (ushort*)(ws + 2034304);       // 100000*128 bf16
    ushort* c0     = (ushort*)(ws + 8434304);
    ushort* c1     = (ushort*)(ws + 14834304);
    ushort* hs     = (ushort*)(ws + 21234304);

    // CSR build
    k_count_init<<<(M_NODES + 255) / 256, 256, 0, stream>>>(cnt);
    k_count<<<2048, 256, 0, stream>>>(dst, cnt);
    k_scanA<<<SCAN_NB, 256, 0, stream>>>(cnt, bsum);
    k_scanB<<<1, 128, 0, stream>>>(bsum, off);
    k_scanC<<<SCAN_NB, 256, 0, stream>>>(cnt, bsum, off, cursor, dinv);
    k_fill<<<2048, 256, 0, stream>>>(src, dst, cursor, csr);

    // weight prep
    k_prep<<<128, 256, 0, stream>>>(W_in, Wt_in, 256);
    k_prep<<<64, 256, 0, stream>>>(W_c0, Wt_c0, 128);
    k_prep<<<64, 256, 0, stream>>>(W_c1, Wt_c1, 128);

    const int GB = (M_NODES + 127) / 128;  // 782

    // input layer: h = bf16(relu(x @ W_in + b_in))
    k_gemm<256, 0, true><<<GB, 256, 0, stream>>>(x, Wt_in, b_in, nullptr, h);

    // conv0
    k_gemm<128, 1, false><<<GB, 256, 0, stream>>>(h, Wt_c0, nullptr, dinv, hs);
    k_gather<<<(M_NODES + 3) / 4, 256, 0, stream>>>(hs, csr, off, dinv, b_c0, c0);

    // conv1
    k_gemm<128, 1, false><<<GB, 256, 0, stream>>>(c0, Wt_c1, nullptr, dinv, hs);
    k_gather<<<(M_NODES + 3) / 4, 256, 0, stream>>>(hs, csr, off, dinv, b_c1, c1);

    // output head
    k_out<<<1024, 256, 0, stream>>>(h, c0, c1, W_out, b_out, out);
}

// Round 5
// 379.159 us; speedup vs baseline: 4.4928x; 1.3127x over previous
//
#include <hip/hip_runtime.h>
#include <hip/hip_bf16.h>

#define M_NODES 100000
#define N_EDGES 1600000
#define SCAN_NB 98   // ceil(100000 / 1024)
#define GB 782       // gemm blocks: ceil(100000/128)
#define CB 2048      // count/fill blocks

typedef __attribute__((ext_vector_type(8))) short short8;
typedef __attribute__((ext_vector_type(4))) float f32x4;
typedef __attribute__((address_space(3))) void lds_t;
typedef const __attribute__((address_space(1))) void gld_t;

__device__ __forceinline__ ushort f2bf(float f) {
    union { float f; uint u; } x; x.f = f;
    uint r = x.u + 0x7fffu + ((x.u >> 16) & 1u);   // RNE
    return (ushort)(r >> 16);
}
__device__ __forceinline__ float bflo(uint v) {
    union { uint u; float f; } x; x.u = v << 16; return x.f;
}
__device__ __forceinline__ float bfhi(uint v) {
    union { uint u; float f; } x; x.u = v & 0xffff0000u; return x.f;
}

// ---------------------------------------------------------------------------
// fused weight prep (transpose+bf16) + cnt zeroing
// blocks 0..127: Wt_in; 128..191: Wt_c0; 192..255: Wt_c1; 256..353: zero cnt
// ---------------------------------------------------------------------------
__global__ void __launch_bounds__(256)
k_prep_all(const float* __restrict__ W_in, const float* __restrict__ W_c0,
           const float* __restrict__ W_c1, ushort* __restrict__ Wt_in,
           ushort* __restrict__ Wt_c0, ushort* __restrict__ Wt_c1,
           int* __restrict__ cnt) {
    const int b = blockIdx.x, t = threadIdx.x;
    if (b < 128) {
        int i = b * 256 + t;              // [0, 32768): c = i>>8, k = i&255
        Wt_in[i] = f2bf(W_in[(size_t)(i & 255) * 128 + (i >> 8)]);
    } else if (b < 192) {
        int i = (b - 128) * 256 + t;      // [0, 16384): c = i>>7, k = i&127
        Wt_c0[i] = f2bf(W_c0[(size_t)(i & 127) * 128 + (i >> 7)]);
    } else if (b < 256) {
        int i = (b - 192) * 256 + t;
        Wt_c1[i] = f2bf(W_c1[(size_t)(i & 127) * 128 + (i >> 7)]);
    } else {
        int base = (b - 256) * 1024 + t * 4;
#pragma unroll
        for (int j = 0; j < 4; ++j)
            if (base + j < M_NODES) cnt[base + j] = 0;
    }
}

// ---------------------------------------------------------------------------
// 3-phase exclusive scan (off) + dinv
// ---------------------------------------------------------------------------
__global__ void __launch_bounds__(256)
k_scanA(const int* __restrict__ cnt, int* __restrict__ bsum) {
    __shared__ int sh[256];
    const int b = blockIdx.x, t = threadIdx.x;
    int base = b * 1024 + t * 4;
    int s = 0;
#pragma unroll
    for (int j = 0; j < 4; ++j) {
        int i = base + j;
        if (i < M_NODES) s += cnt[i];
    }
    sh[t] = s;
    __syncthreads();
    for (int o = 128; o; o >>= 1) {
        if (t < o) sh[t] += sh[t + o];
        __syncthreads();
    }
    if (t == 0) bsum[b] = sh[0];
}

__global__ void __launch_bounds__(128)
k_scanB(int* __restrict__ bsum, int* __restrict__ off) {
    __shared__ int sh[128];
    const int t = threadIdx.x;
    int v = (t < SCAN_NB) ? bsum[t] : 0;
    sh[t] = v;
    __syncthreads();
    for (int o = 1; o < 128; o <<= 1) {
        int u = (t >= o) ? sh[t - o] : 0;
        __syncthreads();
        sh[t] += u;
        __syncthreads();
    }
    if (t < SCAN_NB) bsum[t] = sh[t] - v;  // exclusive
    if (t == 0) off[M_NODES] = N_EDGES;
}

__global__ void __launch_bounds__(256)
k_scanC(const int* __restrict__ cnt, const int* __restrict__ bsum,
        int* __restrict__ off, float* __restrict__ dinv) {
    __shared__ int sh[256];
    const int b = blockIdx.x, t = threadIdx.x;
    int base = b * 1024 + t * 4;
    int loc[4];
    int s = 0;
#pragma unroll
    for (int j = 0; j < 4; ++j) {
        int i = base + j;
        loc[j] = (i < M_NODES) ? cnt[i] : 0;
        s += loc[j];
    }
    sh[t] = s;
    __syncthreads();
    for (int o = 1; o < 256; o <<= 1) {
        int u = (t >= o) ? sh[t - o] : 0;
        __syncthreads();
        sh[t] += u;
        __syncthreads();
    }
    int run = bsum[b] + sh[t] - s;
#pragma unroll
    for (int j = 0; j < 4; ++j) {
        int i = base + j;
        if (i < M_NODES) {
            off[i] = run;
            dinv[i] = rsqrtf((float)(loc[j] + 1));
            run += loc[j];
        }
    }
}

// ---------------------------------------------------------------------------
// MFMA GEMM body: A[M,K] @ B[K,128], B pre-transposed bf16 Bt[128][K].
// 128x128 tile, BK=64, 4 waves (2x2), 16x16x32 bf16 MFMA, 4x4 frags/wave.
// MODE 0: out = bf16(relu(A@B + bias));  MODE 1: out = bf16((A@B)*dinv[row])
// ---------------------------------------------------------------------------
template <int K, int MODE, bool AF32>
__device__ __forceinline__ void
gemm_body(int bid, const void* __restrict__ Av, const ushort* __restrict__ Bt,
          const float* __restrict__ bias, const float* __restrict__ dinv,
          ushort* __restrict__ out) {
    __shared__ ushort As[128 * 64];   // [row][k] 16 KB
    __shared__ ushort Bs[128 * 64];   // [col][k] 16 KB
    const int t = threadIdx.x;
    const int lane = t & 63, w = t >> 6;
    const int wr = w >> 1, wc = w & 1;
    const int l15 = lane & 15, l4 = lane >> 4;
    const int row0 = bid * 128;

    f32x4 acc[4][4] = {};

    for (int k0 = 0; k0 < K; k0 += 64) {
#pragma unroll
        for (int i = 0; i < 4; ++i) {
            int idx = (i * 256 + t) * 8;          // bf16 elem index in tile
            int col = idx >> 6, kc = idx & 63;
            __builtin_amdgcn_global_load_lds(
                (gld_t*)(Bt + (size_t)col * K + k0 + kc),
                (lds_t*)(Bs + idx), 16, 0, 0);
        }
        if (AF32) {
            const float* A = (const float*)Av;
#pragma unroll
            for (int i = 0; i < 4; ++i) {
                int idx = (i * 256 + t) * 8;
                int r = idx >> 6, c = idx & 63;
                int gr = row0 + r; gr = gr < M_NODES ? gr : M_NODES - 1;
                const float4* gp = (const float4*)(A + (size_t)gr * K + k0 + c);
                float4 v0 = gp[0], v1 = gp[1];
                short8 p;
                p[0] = (short)f2bf(v0.x); p[1] = (short)f2bf(v0.y);
                p[2] = (short)f2bf(v0.z); p[3] = (short)f2bf(v0.w);
                p[4] = (short)f2bf(v1.x); p[5] = (short)f2bf(v1.y);
                p[6] = (short)f2bf(v1.z); p[7] = (short)f2bf(v1.w);
                *reinterpret_cast<short8*>(&As[idx]) = p;
            }
        } else {
            const ushort* A = (const ushort*)Av;
#pragma unroll
            for (int i = 0; i < 4; ++i) {
                int idx = (i * 256 + t) * 8;
                int r = idx >> 6, c = idx & 63;
                int gr = row0 + r; gr = gr < M_NODES ? gr : M_NODES - 1;
                __builtin_amdgcn_global_load_lds(
                    (gld_t*)(A + (size_t)gr * K + k0 + c),
                    (lds_t*)(As + idx), 16, 0, 0);
            }
        }
        __syncthreads();
#pragma unroll
        for (int kk = 0; kk < 2; ++kk) {
            short8 af[4], bw[4];
#pragma unroll
            for (int m = 0; m < 4; ++m)
                af[m] = *reinterpret_cast<const short8*>(
                    &As[(wr * 64 + m * 16 + l15) * 64 + kk * 32 + l4 * 8]);
#pragma unroll
            for (int n = 0; n < 4; ++n)
                bw[n] = *reinterpret_cast<const short8*>(
                    &Bs[(wc * 64 + n * 16 + l15) * 64 + kk * 32 + l4 * 8]);
#pragma unroll
            for (int m = 0; m < 4; ++m)
#pragma unroll
                for (int n = 0; n < 4; ++n)
                    acc[m][n] = __builtin_amdgcn_mfma_f32_16x16x32_bf16(
                        af[m], bw[n], acc[m][n], 0, 0, 0);
        }
        __syncthreads();
    }

    // epilogue: C[row][col], col = lane&15, row = (lane>>4)*4 + j
#pragma unroll
    for (int m = 0; m < 4; ++m) {
#pragma unroll
        for (int j = 0; j < 4; ++j) {
            int r = row0 + wr * 64 + m * 16 + l4 * 4 + j;
            if (r < M_NODES) {
                float sc = (MODE == 1) ? dinv[r] : 0.f;
#pragma unroll
                for (int n = 0; n < 4; ++n) {
                    int c = wc * 64 + n * 16 + l15;
                    float v = acc[m][n][j];
                    if (MODE == 0) v = fmaxf(v + bias[c], 0.f);
                    else v *= sc;
                    out[(size_t)r * 128 + c] = f2bf(v);
                }
            }
        }
    }
}

template <int K, int MODE, bool AF32>
__global__ void __launch_bounds__(256)
k_gemm(const void* __restrict__ Av, const ushort* __restrict__ Bt,
       const float* __restrict__ bias, const float* __restrict__ dinv,
       ushort* __restrict__ out) {
    gemm_body<K, MODE, AF32>(blockIdx.x, Av, Bt, bias, dinv, out);
}

// ---------------------------------------------------------------------------
// phase 1: input GEMM (blocks < GB)  ||  degree count + rank store (rest)
// ---------------------------------------------------------------------------
__global__ void __launch_bounds__(256)
k_phase1(const float* __restrict__ x, const ushort* __restrict__ Wt_in,
         const float* __restrict__ b_in, ushort* __restrict__ h,
         const int* __restrict__ dst, int* __restrict__ cnt,
         ushort* __restrict__ rank) {
    if (blockIdx.x < GB) {
        gemm_body<256, 0, true>(blockIdx.x, x, Wt_in, b_in, nullptr, h);
    } else {
        const int bid = blockIdx.x - GB;
        for (int e = bid * 256 + threadIdx.x; e < N_EDGES; e += CB * 256)
            rank[e] = (ushort)atomicAdd(&cnt[dst[e]], 1);
    }
}

// ---------------------------------------------------------------------------
// phase 3: conv0 GEMM (blocks < GB)  ||  atomic-free CSR fill (rest)
// ---------------------------------------------------------------------------
__global__ void __launch_bounds__(256)
k_phase3(const ushort* __restrict__ h, const ushort* __restrict__ Wt_c0,
         const float* __restrict__ dinv, ushort* __restrict__ hs,
         const int* __restrict__ src, const int* __restrict__ dst,
         const int* __restrict__ off, const ushort* __restrict__ rank,
         int* __restrict__ csr) {
    if (blockIdx.x < GB) {
        gemm_body<128, 1, false>(blockIdx.x, h, Wt_c0, nullptr, dinv, hs);
    } else {
        const int bid = blockIdx.x - GB;
        for (int e = bid * 256 + threadIdx.x; e < N_EDGES; e += CB * 256)
            csr[off[dst[e]] + (int)rank[e]] = src[e];
    }
}

// ---------------------------------------------------------------------------
// gather-aggregate (bf16): one wave per node, uint (2 bf16) per lane
// ---------------------------------------------------------------------------
__global__ void __launch_bounds__(256)
k_gather(const ushort* __restrict__ hs, const int* __restrict__ csr,
         const int* __restrict__ off, const float* __restrict__ dinv,
         const float* __restrict__ bias, ushort* __restrict__ out) {
    const int wid = threadIdx.x >> 6;
    const int lane = threadIdx.x & 63;
    const int n = blockIdx.x * 4 + wid;
    if (n >= M_NODES) return;

    const uint* hs2 = (const uint*)hs;
    uint self = hs2[(size_t)n * 64 + lane];
    float ax = bflo(self), ay = bfhi(self);
    const int beg = off[n], end = off[n + 1];

    for (int b = beg; b < end; b += 64) {
        int m = end - b; if (m > 64) m = 64;
        int idx = (lane < m) ? csr[b + lane] : 0;
        for (int i = 0; i < m; ++i) {
            int s = __shfl(idx, i);
            uint v = hs2[(size_t)s * 64 + lane];
            ax += bflo(v);
            ay += bfhi(v);
        }
    }

    float di = dinv[n];
    float2 bb = ((const float2*)bias)[lane];
    uint rx = f2bf(fmaxf(fmaf(ax, di, bb.x), 0.f));
    uint ry = f2bf(fmaxf(fmaf(ay, di, bb.y), 0.f));
    ((uint*)out)[(size_t)n * 64 + lane] = rx | (ry << 16);
}

// ---------------------------------------------------------------------------
// output head (bf16 inputs): out[n] = [h|c0|c1][n] . W_out + b_out
// ---------------------------------------------------------------------------
__global__ void __launch_bounds__(256)
k_out(const ushort* __restrict__ h, const ushort* __restrict__ c0,
      const ushort* __restrict__ c1, const float* __restrict__ Wout,
      const float* __restrict__ bout, float* __restrict__ out) {
    const int lane = threadIdx.x & 63;
    const int wid = threadIdx.x >> 6;
    for (int n = blockIdx.x * 4 + wid; n < M_NODES; n += gridDim.x * 4) {
        size_t base = (size_t)n * 64;
        uint a = ((const uint*)h)[base + lane];
        uint b = ((const uint*)c0)[base + lane];
        uint c = ((const uint*)c1)[base + lane];
        int ch = lane * 2;
        float v = bflo(a) * Wout[ch]       + bfhi(a) * Wout[ch + 1] +
                  bflo(b) * Wout[128 + ch] + bfhi(b) * Wout[128 + ch + 1] +
                  bflo(c) * Wout[256 + ch] + bfhi(c) * Wout[256 + ch + 1];
#pragma unroll
        for (int o = 32; o; o >>= 1) v += __shfl_down(v, o);
        if (lane == 0) out[n] = v + bout[0];
    }
}

// ---------------------------------------------------------------------------
extern "C" void kernel_launch(void* const* d_in, const int* in_sizes, int n_in,
                              void* d_out, int out_size, void* d_ws, size_t ws_size,
                              hipStream_t stream) {
    const float* x     = (const float*)d_in[0];
    const int*   eidx  = (const int*)d_in[1];
    const float* W_in  = (const float*)d_in[2];
    const float* b_in  = (const float*)d_in[3];
    const float* W_c0  = (const float*)d_in[4];
    const float* b_c0  = (const float*)d_in[5];
    const float* W_c1  = (const float*)d_in[6];
    const float* b_c1  = (const float*)d_in[7];
    const float* W_out = (const float*)d_in[8];
    const float* b_out = (const float*)d_in[9];
    float* out = (float*)d_out;

    const int* src = eidx;
    const int* dst = eidx + N_EDGES;

    // workspace layout (4-byte units)
    float*  ws     = (float*)d_ws;
    float*  dinv   = ws;                            // 100352
    int*    cnt    = (int*)(ws + 100352);           // 100352
    int*    off    = (int*)(ws + 200704);           // 100352 (N+1 used)
    int*    bsum   = (int*)(ws + 301056);           // 128
    int*    csr    = (int*)(ws + 301184);           // 1600000
    ushort* Wt_in  = (ushort*)(ws + 1901184);       // 32768 bf16
    ushort* Wt_c0  = (ushort*)(ws + 1917568);       // 16384 bf16
    ushort* Wt_c1  = (ushort*)(ws + 1925760);       // 16384 bf16
    ushort* h      = (ushort*)(ws + 1933952);       // 12.8M bf16
    ushort* c0     = (ushort*)(ws + 8333952);
    ushort* c1     = (ushort*)(ws + 14733952);
    ushort* hs     = (ushort*)(ws + 21133952);
    // rank aliases c1 (disjoint lifetimes: rank dead after phase3; c1 written in gather1)
    ushort* rank   = (ushort*)(ws + 14733952);      // 1.6M bf16-sized slots

    // weight prep + cnt zero
    k_prep_all<<<354, 256, 0, stream>>>(W_in, W_c0, W_c1, Wt_in, Wt_c0, Wt_c1, cnt);

    // phase 1: input GEMM || count+rank
    k_phase1<<<GB + CB, 256, 0, stream>>>(x, Wt_in, b_in, h, dst, cnt, rank);

    // scan: cnt -> off, dinv
    k_scanA<<<SCAN_NB, 256, 0, stream>>>(cnt, bsum);
    k_scanB<<<1, 128, 0, stream>>>(bsum, off);
    k_scanC<<<SCAN_NB, 256, 0, stream>>>(cnt, bsum, off, dinv);

    // phase 3: conv0 GEMM || CSR fill (atomic-free)
    k_phase3<<<GB + CB, 256, 0, stream>>>(h, Wt_c0, dinv, hs, src, dst, off, rank, csr);

    // conv0 aggregate
    k_gather<<<(M_NODES + 3) / 4, 256, 0, stream>>>(hs, csr, off, dinv, b_c0, c0);

    // conv1
    k_gemm<128, 1, false><<<GB, 256, 0, stream>>>(c0, Wt_c1, nullptr, dinv, hs);
    k_gather<<<(M_NODES + 3) / 4, 256, 0, stream>>>(hs, csr, off, dinv, b_c1, c1);

    // output head
    k_out<<<1024, 256, 0, stream>>>(h, c0, c1, W_out, b_out, out);
}

// Round 6
// 363.249 us; speedup vs baseline: 4.6896x; 1.0438x over previous
//
#include <hip/hip_runtime.h>
#include <hip/hip_bf16.h>

#define M_NODES 100000
#define N_EDGES 1600000
#define SCAN_NB 98    // ceil(100000 / 1024)
#define GB 1563       // gemm blocks: ceil(100000/64)
#define CB 2048       // count/fill blocks

typedef __attribute__((ext_vector_type(8))) short short8;
typedef __attribute__((ext_vector_type(4))) float f32x4;
typedef __attribute__((address_space(3))) void lds_t;
typedef const __attribute__((address_space(1))) void gld_t;

__device__ __forceinline__ ushort f2bf(float f) {
    union { float f; uint u; } x; x.f = f;
    uint r = x.u + 0x7fffu + ((x.u >> 16) & 1u);   // RNE
    return (ushort)(r >> 16);
}
__device__ __forceinline__ float bflo(uint v) {
    union { uint u; float f; } x; x.u = v << 16; return x.f;
}
__device__ __forceinline__ float bfhi(uint v) {
    union { uint u; float f; } x; x.u = v & 0xffff0000u; return x.f;
}

// ---------------------------------------------------------------------------
// fused weight prep (transpose+bf16) + cnt zeroing
// ---------------------------------------------------------------------------
__global__ void __launch_bounds__(256)
k_prep_all(const float* __restrict__ W_in, const float* __restrict__ W_c0,
           const float* __restrict__ W_c1, ushort* __restrict__ Wt_in,
           ushort* __restrict__ Wt_c0, ushort* __restrict__ Wt_c1,
           int* __restrict__ cnt) {
    const int b = blockIdx.x, t = threadIdx.x;
    if (b < 128) {
        int i = b * 256 + t;              // c = i>>8, k = i&255
        Wt_in[i] = f2bf(W_in[(size_t)(i & 255) * 128 + (i >> 8)]);
    } else if (b < 192) {
        int i = (b - 128) * 256 + t;      // c = i>>7, k = i&127
        Wt_c0[i] = f2bf(W_c0[(size_t)(i & 127) * 128 + (i >> 7)]);
    } else if (b < 256) {
        int i = (b - 192) * 256 + t;
        Wt_c1[i] = f2bf(W_c1[(size_t)(i & 127) * 128 + (i >> 7)]);
    } else {
        int base = (b - 256) * 1024 + t * 4;
#pragma unroll
        for (int j = 0; j < 4; ++j)
            if (base + j < M_NODES) cnt[base + j] = 0;
    }
}

// ---------------------------------------------------------------------------
// 3-phase exclusive scan (off) + dinv
// ---------------------------------------------------------------------------
__global__ void __launch_bounds__(256)
k_scanA(const int* __restrict__ cnt, int* __restrict__ bsum) {
    __shared__ int sh[256];
    const int b = blockIdx.x, t = threadIdx.x;
    int base = b * 1024 + t * 4;
    int s = 0;
#pragma unroll
    for (int j = 0; j < 4; ++j) {
        int i = base + j;
        if (i < M_NODES) s += cnt[i];
    }
    sh[t] = s;
    __syncthreads();
    for (int o = 128; o; o >>= 1) {
        if (t < o) sh[t] += sh[t + o];
        __syncthreads();
    }
    if (t == 0) bsum[b] = sh[0];
}

__global__ void __launch_bounds__(128)
k_scanB(int* __restrict__ bsum, int* __restrict__ off) {
    __shared__ int sh[128];
    const int t = threadIdx.x;
    int v = (t < SCAN_NB) ? bsum[t] : 0;
    sh[t] = v;
    __syncthreads();
    for (int o = 1; o < 128; o <<= 1) {
        int u = (t >= o) ? sh[t - o] : 0;
        __syncthreads();
        sh[t] += u;
        __syncthreads();
    }
    if (t < SCAN_NB) bsum[t] = sh[t] - v;  // exclusive
    if (t == 0) off[M_NODES] = N_EDGES;
}

__global__ void __launch_bounds__(256)
k_scanC(const int* __restrict__ cnt, const int* __restrict__ bsum,
        int* __restrict__ off, float* __restrict__ dinv) {
    __shared__ int sh[256];
    const int b = blockIdx.x, t = threadIdx.x;
    int base = b * 1024 + t * 4;
    int loc[4];
    int s = 0;
#pragma unroll
    for (int j = 0; j < 4; ++j) {
        int i = base + j;
        loc[j] = (i < M_NODES) ? cnt[i] : 0;
        s += loc[j];
    }
    sh[t] = s;
    __syncthreads();
    for (int o = 1; o < 256; o <<= 1) {
        int u = (t >= o) ? sh[t - o] : 0;
        __syncthreads();
        sh[t] += u;
        __syncthreads();
    }
    int run = bsum[b] + sh[t] - s;
#pragma unroll
    for (int j = 0; j < 4; ++j) {
        int i = base + j;
        if (i < M_NODES) {
            off[i] = run;
            dinv[i] = rsqrtf((float)(loc[j] + 1));
            run += loc[j];
        }
    }
}

// ---------------------------------------------------------------------------
// MFMA GEMM body: A[M,K] @ B[K,128], Bt[128][K] bf16.
// 64x128 tile, BK=64, 4 waves (2x2): wave = 32 rows x 64 cols, 2x4 frags.
// 24 KB LDS -> 6 blocks/CU; 1563 blocks -> grid ~6/CU (latency hiding by TLP).
// MODE 0: out = bf16(relu(A@B + bias));  MODE 1: out = bf16((A@B)*dinv[row])
// ---------------------------------------------------------------------------
template <int K, int MODE, bool AF32>
__device__ __forceinline__ void
gemm_body(int bid, const void* __restrict__ Av, const ushort* __restrict__ Bt,
          const float* __restrict__ bias, const float* __restrict__ dinv,
          ushort* __restrict__ out) {
    __shared__ ushort As[64 * 64];    // [row][k] 8 KB
    __shared__ ushort Bs[128 * 64];   // [col][k] 16 KB
    const int t = threadIdx.x;
    const int lane = t & 63, w = t >> 6;
    const int wr = w >> 1, wc = w & 1;
    const int l15 = lane & 15, l4 = lane >> 4;
    const int row0 = bid * 64;

    f32x4 acc[2][4] = {};

    for (int k0 = 0; k0 < K; k0 += 64) {
        // B tile: 128 cols x 64 k = 16 KB, 4 rounds x 256 thr x 16 B
#pragma unroll
        for (int i = 0; i < 4; ++i) {
            int idx = (i * 256 + t) * 8;          // bf16 elem index in tile
            int col = idx >> 6, kc = idx & 63;
            __builtin_amdgcn_global_load_lds(
                (gld_t*)(Bt + (size_t)col * K + k0 + kc),
                (lds_t*)(Bs + idx), 16, 0, 0);
        }
        if (AF32) {
            const float* A = (const float*)Av;
#pragma unroll
            for (int i = 0; i < 2; ++i) {
                int idx = (i * 256 + t) * 8;
                int r = idx >> 6, c = idx & 63;
                int gr = row0 + r; gr = gr < M_NODES ? gr : M_NODES - 1;
                const float4* gp = (const float4*)(A + (size_t)gr * K + k0 + c);
                float4 v0 = gp[0], v1 = gp[1];
                short8 p;
                p[0] = (short)f2bf(v0.x); p[1] = (short)f2bf(v0.y);
                p[2] = (short)f2bf(v0.z); p[3] = (short)f2bf(v0.w);
                p[4] = (short)f2bf(v1.x); p[5] = (short)f2bf(v1.y);
                p[6] = (short)f2bf(v1.z); p[7] = (short)f2bf(v1.w);
                *reinterpret_cast<short8*>(&As[idx]) = p;
            }
        } else {
            const ushort* A = (const ushort*)Av;
#pragma unroll
            for (int i = 0; i < 2; ++i) {
                int idx = (i * 256 + t) * 8;
                int r = idx >> 6, c = idx & 63;
                int gr = row0 + r; gr = gr < M_NODES ? gr : M_NODES - 1;
                __builtin_amdgcn_global_load_lds(
                    (gld_t*)(A + (size_t)gr * K + k0 + c),
                    (lds_t*)(As + idx), 16, 0, 0);
            }
        }
        __syncthreads();
#pragma unroll
        for (int kk = 0; kk < 2; ++kk) {
            short8 af[2], bw[4];
#pragma unroll
            for (int m = 0; m < 2; ++m)
                af[m] = *reinterpret_cast<const short8*>(
                    &As[(wr * 32 + m * 16 + l15) * 64 + kk * 32 + l4 * 8]);
#pragma unroll
            for (int n = 0; n < 4; ++n)
                bw[n] = *reinterpret_cast<const short8*>(
                    &Bs[(wc * 64 + n * 16 + l15) * 64 + kk * 32 + l4 * 8]);
#pragma unroll
            for (int m = 0; m < 2; ++m)
#pragma unroll
                for (int n = 0; n < 4; ++n)
                    acc[m][n] = __builtin_amdgcn_mfma_f32_16x16x32_bf16(
                        af[m], bw[n], acc[m][n], 0, 0, 0);
        }
        __syncthreads();
    }

    // epilogue: C[row][col], col = lane&15, row = (lane>>4)*4 + j
#pragma unroll
    for (int m = 0; m < 2; ++m) {
#pragma unroll
        for (int j = 0; j < 4; ++j) {
            int r = row0 + wr * 32 + m * 16 + l4 * 4 + j;
            if (r < M_NODES) {
                float sc = (MODE == 1) ? dinv[r] : 0.f;
#pragma unroll
                for (int n = 0; n < 4; ++n) {
                    int c = wc * 64 + n * 16 + l15;
                    float v = acc[m][n][j];
                    if (MODE == 0) v = fmaxf(v + bias[c], 0.f);
                    else v *= sc;
                    out[(size_t)r * 128 + c] = f2bf(v);
                }
            }
        }
    }
}

template <int K, int MODE, bool AF32>
__global__ void __launch_bounds__(256)
k_gemm(const void* __restrict__ Av, const ushort* __restrict__ Bt,
       const float* __restrict__ bias, const float* __restrict__ dinv,
       ushort* __restrict__ out) {
    gemm_body<K, MODE, AF32>(blockIdx.x, Av, Bt, bias, dinv, out);
}

// ---------------------------------------------------------------------------
// phase 1: input GEMM (blocks < GB)  ||  degree count + rank store (rest)
// ---------------------------------------------------------------------------
__global__ void __launch_bounds__(256)
k_phase1(const float* __restrict__ x, const ushort* __restrict__ Wt_in,
         const float* __restrict__ b_in, ushort* __restrict__ h,
         const int* __restrict__ dst, int* __restrict__ cnt,
         ushort* __restrict__ rank) {
    if (blockIdx.x < GB) {
        gemm_body<256, 0, true>(blockIdx.x, x, Wt_in, b_in, nullptr, h);
    } else {
        const int bid = blockIdx.x - GB;
        for (int e = bid * 256 + threadIdx.x; e < N_EDGES; e += CB * 256)
            rank[e] = (ushort)atomicAdd(&cnt[dst[e]], 1);
    }
}

// ---------------------------------------------------------------------------
// phase 3: conv0 GEMM (blocks < GB)  ||  atomic-free CSR fill (rest)
// ---------------------------------------------------------------------------
__global__ void __launch_bounds__(256)
k_phase3(const ushort* __restrict__ h, const ushort* __restrict__ Wt_c0,
         const float* __restrict__ dinv, ushort* __restrict__ hs,
         const int* __restrict__ src, const int* __restrict__ dst,
         const int* __restrict__ off, const ushort* __restrict__ rank,
         int* __restrict__ csr) {
    if (blockIdx.x < GB) {
        gemm_body<128, 1, false>(blockIdx.x, h, Wt_c0, nullptr, dinv, hs);
    } else {
        const int bid = blockIdx.x - GB;
        for (int e = bid * 256 + threadIdx.x; e < N_EDGES; e += CB * 256)
            csr[off[dst[e]] + (int)rank[e]] = src[e];
    }
}

// ---------------------------------------------------------------------------
// gather-aggregate (bf16): one wave per node, uint (2 bf16) per lane
// ---------------------------------------------------------------------------
__global__ void __launch_bounds__(256)
k_gather(const ushort* __restrict__ hs, const int* __restrict__ csr,
         const int* __restrict__ off, const float* __restrict__ dinv,
         const float* __restrict__ bias, ushort* __restrict__ out) {
    const int wid = threadIdx.x >> 6;
    const int lane = threadIdx.x & 63;
    const int n = blockIdx.x * 4 + wid;
    if (n >= M_NODES) return;

    const uint* hs2 = (const uint*)hs;
    uint self = hs2[(size_t)n * 64 + lane];
    float ax = bflo(self), ay = bfhi(self);
    const int beg = off[n], end = off[n + 1];

    for (int b = beg; b < end; b += 64) {
        int m = end - b; if (m > 64) m = 64;
        int idx = (lane < m) ? csr[b + lane] : 0;
        for (int i = 0; i < m; ++i) {
            int s = __shfl(idx, i);
            uint v = hs2[(size_t)s * 64 + lane];
            ax += bflo(v);
            ay += bfhi(v);
        }
    }

    float di = dinv[n];
    float2 bb = ((const float2*)bias)[lane];
    uint rx = f2bf(fmaxf(fmaf(ax, di, bb.x), 0.f));
    uint ry = f2bf(fmaxf(fmaf(ay, di, bb.y), 0.f));
    ((uint*)out)[(size_t)n * 64 + lane] = rx | (ry << 16);
}

// ---------------------------------------------------------------------------
// gather1 + output head fused: compute c1 row in regs, emit out[n] directly
// ---------------------------------------------------------------------------
__global__ void __launch_bounds__(256)
k_gather_out(const ushort* __restrict__ hs, const int* __restrict__ csr,
             const int* __restrict__ off, const float* __restrict__ dinv,
             const float* __restrict__ bias, const ushort* __restrict__ h,
             const ushort* __restrict__ c0, const float* __restrict__ Wout,
             const float* __restrict__ bout, float* __restrict__ out) {
    const int wid = threadIdx.x >> 6;
    const int lane = threadIdx.x & 63;
    const int n = blockIdx.x * 4 + wid;
    if (n >= M_NODES) return;

    const uint* hs2 = (const uint*)hs;
    uint self = hs2[(size_t)n * 64 + lane];
    float ax = bflo(self), ay = bfhi(self);
    const int beg = off[n], end = off[n + 1];

    for (int b = beg; b < end; b += 64) {
        int m = end - b; if (m > 64) m = 64;
        int idx = (lane < m) ? csr[b + lane] : 0;
        for (int i = 0; i < m; ++i) {
            int s = __shfl(idx, i);
            uint v = hs2[(size_t)s * 64 + lane];
            ax += bflo(v);
            ay += bfhi(v);
        }
    }

    float di = dinv[n];
    float2 bb = ((const float2*)bias)[lane];
    float cx = fmaxf(fmaf(ax, di, bb.x), 0.f);   // c1[n][2*lane]   (fp32)
    float cy = fmaxf(fmaf(ay, di, bb.y), 0.f);   // c1[n][2*lane+1]

    size_t base = (size_t)n * 64;
    uint a = ((const uint*)h)[base + lane];
    uint b2 = ((const uint*)c0)[base + lane];
    int ch = lane * 2;
    float v = bflo(a) * Wout[ch]        + bfhi(a) * Wout[ch + 1] +
              bflo(b2) * Wout[128 + ch] + bfhi(b2) * Wout[128 + ch + 1] +
              cx * Wout[256 + ch]       + cy * Wout[256 + ch + 1];
#pragma unroll
    for (int o = 32; o; o >>= 1) v += __shfl_down(v, o);
    if (lane == 0) out[n] = v + bout[0];
}

// ---------------------------------------------------------------------------
extern "C" void kernel_launch(void* const* d_in, const int* in_sizes, int n_in,
                              void* d_out, int out_size, void* d_ws, size_t ws_size,
                              hipStream_t stream) {
    const float* x     = (const float*)d_in[0];
    const int*   eidx  = (const int*)d_in[1];
    const float* W_in  = (const float*)d_in[2];
    const float* b_in  = (const float*)d_in[3];
    const float* W_c0  = (const float*)d_in[4];
    const float* b_c0  = (const float*)d_in[5];
    const float* W_c1  = (const float*)d_in[6];
    const float* b_c1  = (const float*)d_in[7];
    const float* W_out = (const float*)d_in[8];
    const float* b_out = (const float*)d_in[9];
    float* out = (float*)d_out;

    const int* src = eidx;
    const int* dst = eidx + N_EDGES;

    // workspace layout (4-byte units)
    float*  ws     = (float*)d_ws;
    float*  dinv   = ws;                            // 100352
    int*    cnt    = (int*)(ws + 100352);           // 100352
    int*    off    = (int*)(ws + 200704);           // 100352 (N+1 used)
    int*    bsum   = (int*)(ws + 301056);           // 128
    int*    csr    = (int*)(ws + 301184);           // 1600000
    ushort* Wt_in  = (ushort*)(ws + 1901184);       // 32768 bf16
    ushort* Wt_c0  = (ushort*)(ws + 1917568);       // 16384 bf16
    ushort* Wt_c1  = (ushort*)(ws + 1925760);       // 16384 bf16
    ushort* h      = (ushort*)(ws + 1933952);       // 12.8M bf16
    ushort* c0     = (ushort*)(ws + 8333952);
    ushort* rank   = (ushort*)(ws + 14733952);      // 1.6M (old c1 slot)
    ushort* hs     = (ushort*)(ws + 21133952);

    // weight prep + cnt zero
    k_prep_all<<<354, 256, 0, stream>>>(W_in, W_c0, W_c1, Wt_in, Wt_c0, Wt_c1, cnt);

    // phase 1: input GEMM || count+rank
    k_phase1<<<GB + CB, 256, 0, stream>>>(x, Wt_in, b_in, h, dst, cnt, rank);

    // scan: cnt -> off, dinv
    k_scanA<<<SCAN_NB, 256, 0, stream>>>(cnt, bsum);
    k_scanB<<<1, 128, 0, stream>>>(bsum, off);
    k_scanC<<<SCAN_NB, 256, 0, stream>>>(cnt, bsum, off, dinv);

    // phase 3: conv0 GEMM || CSR fill (atomic-free)
    k_phase3<<<GB + CB, 256, 0, stream>>>(h, Wt_c0, dinv, hs, src, dst, off, rank, csr);

    // conv0 aggregate
    k_gather<<<(M_NODES + 3) / 4, 256, 0, stream>>>(hs, csr, off, dinv, b_c0, c0);

    // conv1 GEMM
    k_gemm<128, 1, false><<<GB, 256, 0, stream>>>(c0, Wt_c1, nullptr, dinv, hs);

    // conv1 aggregate + output head (fused)
    k_gather_out<<<(M_NODES + 3) / 4, 256, 0, stream>>>(hs, csr, off, dinv, b_c1,
                                                        h, c0, W_out, b_out, out);
}

// Round 7
// 305.123 us; speedup vs baseline: 5.5830x; 1.1905x over previous
//
#include <hip/hip_runtime.h>
#include <hip/hip_bf16.h>

#define M_NODES 100000
#define N_EDGES 1600000
#define SCAN_NB 98    // ceil(100000 / 1024)
#define GB 1563       // gemm blocks: ceil(100000/64)
#define CB 2048       // count/fill blocks

typedef __attribute__((ext_vector_type(8))) short short8;
typedef __attribute__((ext_vector_type(4))) float f32x4;
typedef __attribute__((address_space(3))) void lds_t;
typedef const __attribute__((address_space(1))) void gld_t;

__device__ __forceinline__ ushort f2bf(float f) {
    union { float f; uint u; } x; x.f = f;
    uint r = x.u + 0x7fffu + ((x.u >> 16) & 1u);   // RNE
    return (ushort)(r >> 16);
}
__device__ __forceinline__ float bflo(uint v) {
    union { uint u; float f; } x; x.u = v << 16; return x.f;
}
__device__ __forceinline__ float bfhi(uint v) {
    union { uint u; float f; } x; x.u = v & 0xffff0000u; return x.f;
}

// ---------------------------------------------------------------------------
// fused weight prep (transpose+bf16) + cnt zeroing
// ---------------------------------------------------------------------------
__global__ void __launch_bounds__(256)
k_prep_all(const float* __restrict__ W_in, const float* __restrict__ W_c0,
           const float* __restrict__ W_c1, ushort* __restrict__ Wt_in,
           ushort* __restrict__ Wt_c0, ushort* __restrict__ Wt_c1,
           int* __restrict__ cnt) {
    const int b = blockIdx.x, t = threadIdx.x;
    if (b < 128) {
        int i = b * 256 + t;              // c = i>>8, k = i&255
        Wt_in[i] = f2bf(W_in[(size_t)(i & 255) * 128 + (i >> 8)]);
    } else if (b < 192) {
        int i = (b - 128) * 256 + t;      // c = i>>7, k = i&127
        Wt_c0[i] = f2bf(W_c0[(size_t)(i & 127) * 128 + (i >> 7)]);
    } else if (b < 256) {
        int i = (b - 192) * 256 + t;
        Wt_c1[i] = f2bf(W_c1[(size_t)(i & 127) * 128 + (i >> 7)]);
    } else {
        int base = (b - 256) * 1024 + t * 4;
#pragma unroll
        for (int j = 0; j < 4; ++j)
            if (base + j < M_NODES) cnt[base + j] = 0;
    }
}

// ---------------------------------------------------------------------------
// 3-phase exclusive scan (off) + dinv
// ---------------------------------------------------------------------------
__global__ void __launch_bounds__(256)
k_scanA(const int* __restrict__ cnt, int* __restrict__ bsum) {
    __shared__ int sh[256];
    const int b = blockIdx.x, t = threadIdx.x;
    int base = b * 1024 + t * 4;
    int s = 0;
#pragma unroll
    for (int j = 0; j < 4; ++j) {
        int i = base + j;
        if (i < M_NODES) s += cnt[i];
    }
    sh[t] = s;
    __syncthreads();
    for (int o = 128; o; o >>= 1) {
        if (t < o) sh[t] += sh[t + o];
        __syncthreads();
    }
    if (t == 0) bsum[b] = sh[0];
}

__global__ void __launch_bounds__(128)
k_scanB(int* __restrict__ bsum, int* __restrict__ off) {
    __shared__ int sh[128];
    const int t = threadIdx.x;
    int v = (t < SCAN_NB) ? bsum[t] : 0;
    sh[t] = v;
    __syncthreads();
    for (int o = 1; o < 128; o <<= 1) {
        int u = (t >= o) ? sh[t - o] : 0;
        __syncthreads();
        sh[t] += u;
        __syncthreads();
    }
    if (t < SCAN_NB) bsum[t] = sh[t] - v;  // exclusive
    if (t == 0) off[M_NODES] = N_EDGES;
}

__global__ void __launch_bounds__(256)
k_scanC(const int* __restrict__ cnt, const int* __restrict__ bsum,
        int* __restrict__ off, float* __restrict__ dinv) {
    __shared__ int sh[256];
    const int b = blockIdx.x, t = threadIdx.x;
    int base = b * 1024 + t * 4;
    int loc[4];
    int s = 0;
#pragma unroll
    for (int j = 0; j < 4; ++j) {
        int i = base + j;
        loc[j] = (i < M_NODES) ? cnt[i] : 0;
        s += loc[j];
    }
    sh[t] = s;
    __syncthreads();
    for (int o = 1; o < 256; o <<= 1) {
        int u = (t >= o) ? sh[t - o] : 0;
        __syncthreads();
        sh[t] += u;
        __syncthreads();
    }
    int run = bsum[b] + sh[t] - s;
#pragma unroll
    for (int j = 0; j < 4; ++j) {
        int i = base + j;
        if (i < M_NODES) {
            off[i] = run;
            dinv[i] = rsqrtf((float)(loc[j] + 1));
            run += loc[j];
        }
    }
}

// ---------------------------------------------------------------------------
// MFMA GEMM body: A[M,K] @ B[K,128], Bt[128][K] bf16.
// 64x128 tile, BK=64, 4 waves (2x2): wave = 32 rows x 64 cols, 2x4 frags.
// ---------------------------------------------------------------------------
template <int K, int MODE, bool AF32>
__device__ __forceinline__ void
gemm_body(int bid, const void* __restrict__ Av, const ushort* __restrict__ Bt,
          const float* __restrict__ bias, const float* __restrict__ dinv,
          ushort* __restrict__ out) {
    __shared__ ushort As[64 * 64];    // [row][k] 8 KB
    __shared__ ushort Bs[128 * 64];   // [col][k] 16 KB
    const int t = threadIdx.x;
    const int lane = t & 63, w = t >> 6;
    const int wr = w >> 1, wc = w & 1;
    const int l15 = lane & 15, l4 = lane >> 4;
    const int row0 = bid * 64;

    f32x4 acc[2][4] = {};

    for (int k0 = 0; k0 < K; k0 += 64) {
#pragma unroll
        for (int i = 0; i < 4; ++i) {
            int idx = (i * 256 + t) * 8;          // bf16 elem index in tile
            int col = idx >> 6, kc = idx & 63;
            __builtin_amdgcn_global_load_lds(
                (gld_t*)(Bt + (size_t)col * K + k0 + kc),
                (lds_t*)(Bs + idx), 16, 0, 0);
        }
        if (AF32) {
            const float* A = (const float*)Av;
#pragma unroll
            for (int i = 0; i < 2; ++i) {
                int idx = (i * 256 + t) * 8;
                int r = idx >> 6, c = idx & 63;
                int gr = row0 + r; gr = gr < M_NODES ? gr : M_NODES - 1;
                const float4* gp = (const float4*)(A + (size_t)gr * K + k0 + c);
                float4 v0 = gp[0], v1 = gp[1];
                short8 p;
                p[0] = (short)f2bf(v0.x); p[1] = (short)f2bf(v0.y);
                p[2] = (short)f2bf(v0.z); p[3] = (short)f2bf(v0.w);
                p[4] = (short)f2bf(v1.x); p[5] = (short)f2bf(v1.y);
                p[6] = (short)f2bf(v1.z); p[7] = (short)f2bf(v1.w);
                *reinterpret_cast<short8*>(&As[idx]) = p;
            }
        } else {
            const ushort* A = (const ushort*)Av;
#pragma unroll
            for (int i = 0; i < 2; ++i) {
                int idx = (i * 256 + t) * 8;
                int r = idx >> 6, c = idx & 63;
                int gr = row0 + r; gr = gr < M_NODES ? gr : M_NODES - 1;
                __builtin_amdgcn_global_load_lds(
                    (gld_t*)(A + (size_t)gr * K + k0 + c),
                    (lds_t*)(As + idx), 16, 0, 0);
            }
        }
        __syncthreads();
#pragma unroll
        for (int kk = 0; kk < 2; ++kk) {
            short8 af[2], bw[4];
#pragma unroll
            for (int m = 0; m < 2; ++m)
                af[m] = *reinterpret_cast<const short8*>(
                    &As[(wr * 32 + m * 16 + l15) * 64 + kk * 32 + l4 * 8]);
#pragma unroll
            for (int n = 0; n < 4; ++n)
                bw[n] = *reinterpret_cast<const short8*>(
                    &Bs[(wc * 64 + n * 16 + l15) * 64 + kk * 32 + l4 * 8]);
#pragma unroll
            for (int m = 0; m < 2; ++m)
#pragma unroll
                for (int n = 0; n < 4; ++n)
                    acc[m][n] = __builtin_amdgcn_mfma_f32_16x16x32_bf16(
                        af[m], bw[n], acc[m][n], 0, 0, 0);
        }
        __syncthreads();
    }

#pragma unroll
    for (int m = 0; m < 2; ++m) {
#pragma unroll
        for (int j = 0; j < 4; ++j) {
            int r = row0 + wr * 32 + m * 16 + l4 * 4 + j;
            if (r < M_NODES) {
                float sc = (MODE == 1) ? dinv[r] : 0.f;
#pragma unroll
                for (int n = 0; n < 4; ++n) {
                    int c = wc * 64 + n * 16 + l15;
                    float v = acc[m][n][j];
                    if (MODE == 0) v = fmaxf(v + bias[c], 0.f);
                    else v *= sc;
                    out[(size_t)r * 128 + c] = f2bf(v);
                }
            }
        }
    }
}

template <int K, int MODE, bool AF32>
__global__ void __launch_bounds__(256)
k_gemm(const void* __restrict__ Av, const ushort* __restrict__ Bt,
       const float* __restrict__ bias, const float* __restrict__ dinv,
       ushort* __restrict__ out) {
    gemm_body<K, MODE, AF32>(blockIdx.x, Av, Bt, bias, dinv, out);
}

// ---------------------------------------------------------------------------
// phase 1: input GEMM (blocks < GB)  ||  degree count + rank store (rest)
// ---------------------------------------------------------------------------
__global__ void __launch_bounds__(256)
k_phase1(const float* __restrict__ x, const ushort* __restrict__ Wt_in,
         const float* __restrict__ b_in, ushort* __restrict__ h,
         const int* __restrict__ dst, int* __restrict__ cnt,
         ushort* __restrict__ rank) {
    if (blockIdx.x < GB) {
        gemm_body<256, 0, true>(blockIdx.x, x, Wt_in, b_in, nullptr, h);
    } else {
        const int bid = blockIdx.x - GB;
        for (int e = bid * 256 + threadIdx.x; e < N_EDGES; e += CB * 256)
            rank[e] = (ushort)atomicAdd(&cnt[dst[e]], 1);
    }
}

// ---------------------------------------------------------------------------
// phase 3: conv0 GEMM (blocks < GB)  ||  atomic-free CSR fill (rest)
// ---------------------------------------------------------------------------
__global__ void __launch_bounds__(256)
k_phase3(const ushort* __restrict__ h, const ushort* __restrict__ Wt_c0,
         const float* __restrict__ dinv, ushort* __restrict__ hs,
         const int* __restrict__ src, const int* __restrict__ dst,
         const int* __restrict__ off, const ushort* __restrict__ rank,
         int* __restrict__ csr) {
    if (blockIdx.x < GB) {
        gemm_body<128, 1, false>(blockIdx.x, h, Wt_c0, nullptr, dinv, hs);
    } else {
        const int bid = blockIdx.x - GB;
        for (int e = bid * 256 + threadIdx.x; e < N_EDGES; e += CB * 256)
            csr[off[dst[e]] + (int)rank[e]] = src[e];
    }
}

// ---------------------------------------------------------------------------
// neighbor accumulation core: 8-way unrolled, 8 independent acc pairs
// (8 row-loads in flight per wave -> MLP instead of serial latency chain)
// ---------------------------------------------------------------------------
__device__ __forceinline__ void
gather_accum(const uint* __restrict__ hs2, const int* __restrict__ csr,
             int beg, int end, int lane, float& ax, float& ay) {
    float px[8] = {}, py[8] = {};
    for (int b = beg; b < end; b += 64) {
        int m = end - b; if (m > 64) m = 64;
        int idx = (lane < m) ? csr[b + lane] : 0;
        int i = 0;
        for (; i + 8 <= m; i += 8) {
            uint v0 = hs2[(size_t)__shfl(idx, i + 0) * 64 + lane];
            uint v1 = hs2[(size_t)__shfl(idx, i + 1) * 64 + lane];
            uint v2 = hs2[(size_t)__shfl(idx, i + 2) * 64 + lane];
            uint v3 = hs2[(size_t)__shfl(idx, i + 3) * 64 + lane];
            uint v4 = hs2[(size_t)__shfl(idx, i + 4) * 64 + lane];
            uint v5 = hs2[(size_t)__shfl(idx, i + 5) * 64 + lane];
            uint v6 = hs2[(size_t)__shfl(idx, i + 6) * 64 + lane];
            uint v7 = hs2[(size_t)__shfl(idx, i + 7) * 64 + lane];
            px[0] += bflo(v0); py[0] += bfhi(v0);
            px[1] += bflo(v1); py[1] += bfhi(v1);
            px[2] += bflo(v2); py[2] += bfhi(v2);
            px[3] += bflo(v3); py[3] += bfhi(v3);
            px[4] += bflo(v4); py[4] += bfhi(v4);
            px[5] += bflo(v5); py[5] += bfhi(v5);
            px[6] += bflo(v6); py[6] += bfhi(v6);
            px[7] += bflo(v7); py[7] += bfhi(v7);
        }
        // remainder: up to 7, still issue all loads before consuming
        uint rv[7]; int rc = 0;
        for (; i < m; ++i) rv[rc++] = hs2[(size_t)__shfl(idx, i) * 64 + lane];
        for (int k = 0; k < rc; ++k) { px[k] += bflo(rv[k]); py[k] += bfhi(rv[k]); }
    }
    ax += ((px[0] + px[1]) + (px[2] + px[3])) + ((px[4] + px[5]) + (px[6] + px[7]));
    ay += ((py[0] + py[1]) + (py[2] + py[3])) + ((py[4] + py[5]) + (py[6] + py[7]));
}

// ---------------------------------------------------------------------------
// gather-aggregate (bf16): one wave per node, uint (2 bf16) per lane
// ---------------------------------------------------------------------------
__global__ void __launch_bounds__(256)
k_gather(const ushort* __restrict__ hs, const int* __restrict__ csr,
         const int* __restrict__ off, const float* __restrict__ dinv,
         const float* __restrict__ bias, ushort* __restrict__ out) {
    const int wid = threadIdx.x >> 6;
    const int lane = threadIdx.x & 63;
    const int n = blockIdx.x * 4 + wid;
    if (n >= M_NODES) return;

    const uint* hs2 = (const uint*)hs;
    uint self = hs2[(size_t)n * 64 + lane];
    float ax = bflo(self), ay = bfhi(self);
    gather_accum(hs2, csr, off[n], off[n + 1], lane, ax, ay);

    float di = dinv[n];
    float2 bb = ((const float2*)bias)[lane];
    uint rx = f2bf(fmaxf(fmaf(ax, di, bb.x), 0.f));
    uint ry = f2bf(fmaxf(fmaf(ay, di, bb.y), 0.f));
    ((uint*)out)[(size_t)n * 64 + lane] = rx | (ry << 16);
}

// ---------------------------------------------------------------------------
// gather1 + output head fused: compute c1 row in regs, emit out[n] directly
// ---------------------------------------------------------------------------
__global__ void __launch_bounds__(256)
k_gather_out(const ushort* __restrict__ hs, const int* __restrict__ csr,
             const int* __restrict__ off, const float* __restrict__ dinv,
             const float* __restrict__ bias, const ushort* __restrict__ h,
             const ushort* __restrict__ c0, const float* __restrict__ Wout,
             const float* __restrict__ bout, float* __restrict__ out) {
    const int wid = threadIdx.x >> 6;
    const int lane = threadIdx.x & 63;
    const int n = blockIdx.x * 4 + wid;
    if (n >= M_NODES) return;

    const uint* hs2 = (const uint*)hs;
    uint self = hs2[(size_t)n * 64 + lane];
    float ax = bflo(self), ay = bfhi(self);
    gather_accum(hs2, csr, off[n], off[n + 1], lane, ax, ay);

    float di = dinv[n];
    float2 bb = ((const float2*)bias)[lane];
    float cx = fmaxf(fmaf(ax, di, bb.x), 0.f);   // c1[n][2*lane]   (fp32)
    float cy = fmaxf(fmaf(ay, di, bb.y), 0.f);   // c1[n][2*lane+1]

    size_t base = (size_t)n * 64;
    uint a = ((const uint*)h)[base + lane];
    uint b2 = ((const uint*)c0)[base + lane];
    int ch = lane * 2;
    float v = bflo(a) * Wout[ch]        + bfhi(a) * Wout[ch + 1] +
              bflo(b2) * Wout[128 + ch] + bfhi(b2) * Wout[128 + ch + 1] +
              cx * Wout[256 + ch]       + cy * Wout[256 + ch + 1];
#pragma unroll
    for (int o = 32; o; o >>= 1) v += __shfl_down(v, o);
    if (lane == 0) out[n] = v + bout[0];
}

// ---------------------------------------------------------------------------
extern "C" void kernel_launch(void* const* d_in, const int* in_sizes, int n_in,
                              void* d_out, int out_size, void* d_ws, size_t ws_size,
                              hipStream_t stream) {
    const float* x     = (const float*)d_in[0];
    const int*   eidx  = (const int*)d_in[1];
    const float* W_in  = (const float*)d_in[2];
    const float* b_in  = (const float*)d_in[3];
    const float* W_c0  = (const float*)d_in[4];
    const float* b_c0  = (const float*)d_in[5];
    const float* W_c1  = (const float*)d_in[6];
    const float* b_c1  = (const float*)d_in[7];
    const float* W_out = (const float*)d_in[8];
    const float* b_out = (const float*)d_in[9];
    float* out = (float*)d_out;

    const int* src = eidx;
    const int* dst = eidx + N_EDGES;

    // workspace layout (4-byte units)
    float*  ws     = (float*)d_ws;
    float*  dinv   = ws;                            // 100352
    int*    cnt    = (int*)(ws + 100352);           // 100352
    int*    off    = (int*)(ws + 200704);           // 100352 (N+1 used)
    int*    bsum   = (int*)(ws + 301056);           // 128
    int*    csr    = (int*)(ws + 301184);           // 1600000
    ushort* Wt_in  = (ushort*)(ws + 1901184);       // 32768 bf16
    ushort* Wt_c0  = (ushort*)(ws + 1917568);       // 16384 bf16
    ushort* Wt_c1  = (ushort*)(ws + 1925760);       // 16384 bf16
    ushort* h      = (ushort*)(ws + 1933952);       // 12.8M bf16
    ushort* c0     = (ushort*)(ws + 8333952);
    ushort* rank   = (ushort*)(ws + 14733952);      // 1.6M
    ushort* hs     = (ushort*)(ws + 21133952);

    // weight prep + cnt zero
    k_prep_all<<<354, 256, 0, stream>>>(W_in, W_c0, W_c1, Wt_in, Wt_c0, Wt_c1, cnt);

    // phase 1: input GEMM || count+rank
    k_phase1<<<GB + CB, 256, 0, stream>>>(x, Wt_in, b_in, h, dst, cnt, rank);

    // scan: cnt -> off, dinv
    k_scanA<<<SCAN_NB, 256, 0, stream>>>(cnt, bsum);
    k_scanB<<<1, 128, 0, stream>>>(bsum, off);
    k_scanC<<<SCAN_NB, 256, 0, stream>>>(cnt, bsum, off, dinv);

    // phase 3: conv0 GEMM || CSR fill (atomic-free)
    k_phase3<<<GB + CB, 256, 0, stream>>>(h, Wt_c0, dinv, hs, src, dst, off, rank, csr);

    // conv0 aggregate
    k_gather<<<(M_NODES + 3) / 4, 256, 0, stream>>>(hs, csr, off, dinv, b_c0, c0);

    // conv1 GEMM
    k_gemm<128, 1, false><<<GB, 256, 0, stream>>>(c0, Wt_c1, nullptr, dinv, hs);

    // conv1 aggregate + output head (fused)
    k_gather_out<<<(M_NODES + 3) / 4, 256, 0, stream>>>(hs, csr, off, dinv, b_c1,
                                                        h, c0, W_out, b_out, out);
}